// Round 12
// baseline (484.440 us; speedup 1.0000x reference)
//
#include <hip/hip_runtime.h>
#include <math.h>

// ---------------------------------------------------------------------------
// Net_37512244363273: 5-level edge-conditioned graph conv + voxel pooling + FC
// Round 12: part0 was grid-limited (256 blocks = 1/CU, 9.7% occupancy, 64 us,
// 1.3 TB/s achieved). Now 1024 tiles x 1024 edges (4/thread) -> 4 blocks/CU,
// latency of the scattered 32B record stores hidden by TLP. cnt0/colscan
// restructured for 1024 tiles. Everything else unchanged from round 11
// (conv0c in-LDS CSR + register accumulation = verified win; segs 1-9 keep
// the XCD-bucketed atomic CSR build; closs via h-stats, L0 fused in part0).
// Output: 80 log_softmax + closs = 81 floats.
// ---------------------------------------------------------------------------

#define NBUCK 8
#define TILES0 1024                // seg0 tiles (1024 edges each)
#define NB0    512                 // seg0 buckets (dst>>7, 128 nodes each)
#define IDXCAP 3072                // per-bucket index capacity (mean 2048)

// ---- segment descriptor for CSR builds (segs 1-9: edge 1-4 + cluster 0-4) --
struct SegArgs {
    const int* idx[10];
    int*       cnt[10];
    int*       rp [10];
    int*       out[10];
    int        n  [10];
    int        nb [10];
    int        shift[10];
    int        tstart[11];
};

struct ScanAux {
    int* tilesum;
    int* tileoff;
    int  sstart[11];
    int  T;
};

// XCD-bucketed histogram (per-element global atomics; small segs only).
__global__ __launch_bounds__(256) void hist_all_k(SegArgs a) {
    int B = blockIdx.x;
    int bucket = B % NBUCK;
    int T = B / NBUCK;
    int s = 0;
    while (s < 9 && T >= a.tstart[s + 1]) s++;
    int i = (T - a.tstart[s]) * 256 + threadIdx.x;
    if (i >= a.n[s]) return;
    int d = a.idx[s][i];
    if ((d >> a.shift[s]) != bucket) return;
    atomicAdd(&a.cnt[s][d], 1);
}

// 3-phase hierarchical scan over segs 1-9 cnt arrays.
__global__ __launch_bounds__(256) void scanA_k(SegArgs a, ScanAux x) {
    int b = blockIdx.x;
    int s = 0;
    while (s < 9 && b >= x.sstart[s + 1]) s++;
    int tloc = b - x.sstart[s];
    int nb = a.nb[s];
    const int* cnt = a.cnt[s];
    int i0 = tloc * 4096 + threadIdx.x * 16;
    int sum = 0;
    #pragma unroll
    for (int k = 0; k < 16; k++) {
        int i = i0 + k;
        if (i < nb) sum += cnt[i];
    }
    #pragma unroll
    for (int o = 32; o; o >>= 1) sum += __shfl_down(sum, o);
    __shared__ int red[4];
    if ((threadIdx.x & 63) == 0) red[threadIdx.x >> 6] = sum;
    __syncthreads();
    if (threadIdx.x == 0)
        x.tilesum[b] = red[0] + red[1] + red[2] + red[3];
}

__global__ __launch_bounds__(64) void scanB_k(SegArgs a, ScanAux x) {
    int lane = threadIdx.x;
    int orig = (lane < x.T) ? x.tilesum[lane] : 0;
    int val = orig;
    #pragma unroll
    for (int d = 1; d < 64; d <<= 1) {
        int v = __shfl_up(val, d);
        if (lane >= d) val += v;
    }
    int excl = val - orig;
    int s = 0;
    while (s < 9 && lane >= x.sstart[s + 1]) s++;
    int segExcl = __shfl(excl, x.sstart[s]);
    if (lane < x.T) {
        x.tileoff[lane] = excl - segExcl;
        if (lane == x.sstart[s + 1] - 1)
            a.rp[s][a.nb[s]] = val - segExcl;
    }
}

__global__ __launch_bounds__(256) void scanC_k(SegArgs a, ScanAux x) {
    int b = blockIdx.x;
    int s = 0;
    while (s < 9 && b >= x.sstart[s + 1]) s++;
    int tloc = b - x.sstart[s];
    int nb = a.nb[s];
    const int* cnt = a.cnt[s];
    int* rp = a.rp[s];
    int i0 = tloc * 4096 + threadIdx.x * 16;
    int v[16];
    int sum = 0;
    #pragma unroll
    for (int k = 0; k < 16; k++) {
        int i = i0 + k;
        v[k] = (i < nb) ? cnt[i] : 0;
        sum += v[k];
    }
    __shared__ int sc[256];
    int acc = sum;
    sc[threadIdx.x] = acc;
    __syncthreads();
    for (int d = 1; d < 256; d <<= 1) {
        int t2 = (threadIdx.x >= d) ? sc[threadIdx.x - d] : 0;
        __syncthreads();
        acc += t2;
        sc[threadIdx.x] = acc;
        __syncthreads();
    }
    int running = x.tileoff[b] + (acc - sum);
    #pragma unroll
    for (int k = 0; k < 16; k++) {
        int i = i0 + k;
        if (i < nb) rp[i] = running;
        running += v[k];
    }
}

// XCD-bucketed countdown-scatter (small segs only).
__global__ __launch_bounds__(256) void scatter_all_k(SegArgs a) {
    int B = blockIdx.x;
    int bucket = B % NBUCK;
    int T = B / NBUCK;
    int s = 0;
    while (s < 9 && T >= a.tstart[s + 1]) s++;
    int i = (T - a.tstart[s]) * 256 + threadIdx.x;
    if (i >= a.n[s]) return;
    int d = a.idx[s][i];
    if ((d >> a.shift[s]) != bucket) return;
    int p = atomicSub(&a.cnt[s][d], 1) - 1;
    a.out[s][a.rp[s][d] + p] = i;
}

// ---------------------------------------------------------------------------
// Seg-0 pipeline: deterministic 512-bucket partition (fused h + L0 stats),
// then fused per-bucket in-LDS CSR + register accumulation conv.
// ---------------------------------------------------------------------------
__global__ __launch_bounds__(256) void cnt0_k(
    const int* __restrict__ dst, int* __restrict__ M)
{
    __shared__ int h[NB0];
    int t = threadIdx.x;
    for (int u = t; u < NB0; u += 256) h[u] = 0;
    __syncthreads();
    int base = blockIdx.x * 1024 + t;
    #pragma unroll
    for (int it = 0; it < 4; it++)
        atomicAdd(&h[dst[base + it * 256] >> 7], 1);      // LDS
    __syncthreads();
    for (int u = t; u < NB0; u += 256) M[(size_t)blockIdx.x * NB0 + u] = h[u];
}

// per-bucket exclusive scan over 1024 tiles: 4 tiles/thread register prefix
// + 256-wide block scan.
__global__ __launch_bounds__(256) void colscan_k(
    const int* __restrict__ M, int* __restrict__ M2, int* __restrict__ colTotal)
{
    int b = blockIdx.x, t = threadIdx.x;
    int v[4];
    int s = 0;
    #pragma unroll
    for (int c = 0; c < 4; c++) {
        v[c] = M[(size_t)(t * 4 + c) * NB0 + b];
        s += v[c];
    }
    __shared__ int sc[256];
    sc[t] = s;
    __syncthreads();
    for (int d = 1; d < 256; d <<= 1) {
        int u = (t >= d) ? sc[t - d] : 0;
        __syncthreads();
        sc[t] += u;
        __syncthreads();
    }
    int run = sc[t] - s;                   // exclusive prefix of this chunk
    #pragma unroll
    for (int c = 0; c < 4; c++) {
        M2[(size_t)(t * 4 + c) * NB0 + b] = run;
        run += v[c];
    }
    if (t == 255) colTotal[b] = run;
}

__global__ __launch_bounds__(512) void bktscan_k(
    const int* __restrict__ colTotal, int* __restrict__ bucketStart)
{
    int t = threadIdx.x;
    int v = colTotal[t];
    __shared__ int sc[NB0];
    sc[t] = v;
    __syncthreads();
    for (int d = 1; d < NB0; d <<= 1) {
        int u = (t >= d) ? sc[t - d] : 0;
        __syncthreads();
        sc[t] += u;
        __syncthreads();
    }
    bucketStart[t] = sc[t] - v;
    if (t == NB0 - 1) bucketStart[NB0] = sc[NB0 - 1];
}

// partition + fused h/tanh + level-0 h-stats. Record (2 x float4):
//   A = (x_src, h0*x, h1*x, h2*x), B = (h3*x, h4*x, 0, 0); key separate.
__global__ __launch_bounds__(256) void part0_k(
    const int* __restrict__ src, const int* __restrict__ dst,
    const float* __restrict__ ea, const float* __restrict__ x0,
    const int* __restrict__ M2, const int* __restrict__ bucketStart,
    int* __restrict__ keys, float4* __restrict__ pay2,
    const float* __restrict__ w1, const float* __restrict__ b1,
    float* __restrict__ H0)
{
    __shared__ int cur[NB0];
    __shared__ float w1s[15], b1s[5];
    __shared__ float red[4][20];
    int t = threadIdx.x;
    for (int u = t; u < NB0; u += 256)
        cur[u] = bucketStart[u] + M2[(size_t)blockIdx.x * NB0 + u];
    if (t < 15) w1s[t] = w1[t];
    if (t >= 32 && t < 37) b1s[t - 32] = b1[t - 32];
    __syncthreads();

    float acc[20];
    #pragma unroll
    for (int i = 0; i < 20; i++) acc[i] = 0.f;

    int base = blockIdx.x * 1024 + t;
    #pragma unroll
    for (int it = 0; it < 4; it++) {
        int i = base + it * 256;
        int d = dst[i];
        float e0 = ea[i * 3], e1 = ea[i * 3 + 1], e2 = ea[i * 3 + 2];
        float h[5];
        #pragma unroll
        for (int k = 0; k < 5; k++)
            h[k] = tanhf(e0 * w1s[k] + e1 * w1s[5 + k] + e2 * w1s[10 + k] + b1s[k]);
        int p = 5;
        #pragma unroll
        for (int k = 0; k < 5; k++) {
            acc[k] += h[k];
            #pragma unroll
            for (int k2 = k; k2 < 5; k2++) acc[p++] += h[k] * h[k2];
        }
        float xv = x0[src[i]];
        int ps = atomicAdd(&cur[d >> 7], 1);              // LDS
        keys[ps] = d;
        pay2[2 * ps]     = make_float4(xv, h[0] * xv, h[1] * xv, h[2] * xv);
        pay2[2 * ps + 1] = make_float4(h[3] * xv, h[4] * xv, 0.f, 0.f);
    }

    // level-0 h-stat reduction: wave shfl -> LDS -> 20 atomics per block
    int wid = t >> 6, lane = t & 63;
    #pragma unroll
    for (int v = 0; v < 20; v++) {
        float s = acc[v];
        #pragma unroll
        for (int o = 32; o; o >>= 1) s += __shfl_down(s, o);
        if (lane == 0) red[wid][v] = s;
    }
    __syncthreads();
    if (t < 20)
        atomicAdd(&H0[t], red[0][t] + red[1][t] + red[2][t] + red[3][t]);
}

// conv0c: one block per 128-node bucket. In-LDS CSR of record indices
// (2 low-contention LDS atomics/record), then per-node register sums.
__global__ __launch_bounds__(256) void conv0c_k(
    const int* __restrict__ keys, const float4* __restrict__ pay2,
    const int* __restrict__ bucketStart,
    const float* __restrict__ w2, const float* __restrict__ b2,
    const float* __restrict__ root, const float* __restrict__ bias,
    const float* __restrict__ x, float* __restrict__ y)
{
    __shared__ float w2s[60], b2s[12], roots[12], biass[12];
    __shared__ int hist[128], st[128], cur[128];
    __shared__ int idxL[IDXCAP];
    int t = threadIdx.x;
    if (t < 60) w2s[t] = w2[t];
    else if (t >= 64  && t < 76)  b2s[t - 64]    = b2[t - 64];
    else if (t >= 128 && t < 140) roots[t - 128] = root[t - 128];
    else if (t >= 192 && t < 204) biass[t - 192] = bias[t - 192];
    if (t < 128) hist[t] = 0;
    __syncthreads();

    int b = blockIdx.x;
    int lo = bucketStart[b], hi = bucketStart[b + 1];
    int bin0 = b << 7;
    for (int j = lo + t; j < hi; j += 256)
        atomicAdd(&hist[keys[j] - bin0], 1);              // LDS
    __syncthreads();
    if (t < 128) st[t] = hist[t];
    __syncthreads();
    for (int d = 1; d < 128; d <<= 1) {
        int u = (t < 128 && t >= d) ? st[t - d] : 0;
        __syncthreads();
        if (t < 128) st[t] += u;
        __syncthreads();
    }
    if (t < 128) cur[t] = st[t] - hist[t];                // exclusive
    __syncthreads();
    for (int j = lo + t; j < hi; j += 256) {
        int rel = keys[j] - bin0;
        int p = atomicAdd(&cur[rel], 1);                  // LDS
        idxL[p] = j;
    }
    __syncthreads();

    if (t < 128) {
        int v = bin0 + t;
        int deg = hist[t];
        int s0 = st[t] - deg;
        float S0 = 0.f, S1 = 0.f, S2 = 0.f, S3 = 0.f, S4 = 0.f, S5 = 0.f;
        for (int jj = s0; jj < s0 + deg; jj++) {
            int j = idxL[jj];
            float4 A = pay2[2 * j], B = pay2[2 * j + 1];
            S0 += A.x; S1 += A.y; S2 += A.z; S3 += A.w;
            S4 += B.x; S5 += B.y;
        }
        float inv = 1.f / fmaxf((float)deg, 1.f);
        float xv = x[v];
        #pragma unroll
        for (int o = 0; o < 12; o++) {
            float msg = b2s[o] * S0 + w2s[o] * S1 + w2s[12 + o] * S2 +
                        w2s[24 + o] * S3 + w2s[36 + o] * S4 + w2s[48 + o] * S5;
            y[v * 12 + o] = msg * inv + xv * roots[o] + biass[o];
        }
    }
}

// ---------------------------------------------------------------------------
// hstats (levels 1-4 only) / wstats: closs via h-statistics.
// ---------------------------------------------------------------------------
struct HArgs {
    const float* eattr[5];
    const float* w1[5];
    const float* b1[5];
    float*       H;
    int          E[5];
    int          bstart[6];
};

__global__ __launch_bounds__(256) void hstats_k(HArgs a) {
    const int K = 32;
    int b = blockIdx.x, l = 0;
    while (l < 4 && b >= a.bstart[l + 1]) l++;
    int bloc = b - a.bstart[l];
    const float* ea = a.eattr[l];
    float w1r[15], b1r[5];
    #pragma unroll
    for (int i = 0; i < 15; i++) w1r[i] = a.w1[l][i];
    #pragma unroll
    for (int i = 0; i < 5; i++)  b1r[i] = a.b1[l][i];
    float acc[20];
    #pragma unroll
    for (int i = 0; i < 20; i++) acc[i] = 0.f;
    int base = bloc * 256 * K + threadIdx.x;
    for (int it = 0; it < K; it++) {
        int e = base + it * 256;
        if (e < a.E[l]) {
            float e0 = ea[e * 3], e1 = ea[e * 3 + 1], e2 = ea[e * 3 + 2];
            float h[5];
            #pragma unroll
            for (int k = 0; k < 5; k++)
                h[k] = tanhf(e0 * w1r[k] + e1 * w1r[5 + k] + e2 * w1r[10 + k] + b1r[k]);
            int p = 5;
            #pragma unroll
            for (int k = 0; k < 5; k++) {
                acc[k] += h[k];
                #pragma unroll
                for (int k2 = k; k2 < 5; k2++) acc[p++] += h[k] * h[k2];
            }
        }
    }
    __shared__ float red[4][20];
    int wid = threadIdx.x >> 6, lane = threadIdx.x & 63;
    #pragma unroll
    for (int v = 0; v < 20; v++) {
        float s = acc[v];
        #pragma unroll
        for (int off = 32; off; off >>= 1) s += __shfl_down(s, off);
        if (lane == 0) red[wid][v] = s;
    }
    __syncthreads();
    if (threadIdx.x < 20) {
        float s = red[0][threadIdx.x] + red[1][threadIdx.x] +
                  red[2][threadIdx.x] + red[3][threadIdx.x];
        atomicAdd(&a.H[l * 20 + threadIdx.x], s);
    }
}

struct WArgs {
    const float* w2[5];
    const float* b2[5];
    const float* H;
    float*       sq;
    int          cico[5];
    int          E[5];
};

__global__ __launch_bounds__(64) void wstats_k(WArgs a) {
    int l = blockIdx.x;
    const float* w2 = a.w2[l];
    const float* b2 = a.b2[l];
    int cico = a.cico[l];
    float d[21];
    #pragma unroll
    for (int i = 0; i < 21; i++) d[i] = 0.f;
    for (int u = threadIdx.x; u < cico; u += 64) {
        float b = b2[u];
        float w[5];
        #pragma unroll
        for (int k = 0; k < 5; k++) w[k] = w2[k * cico + u];
        int p = 0;
        #pragma unroll
        for (int k = 0; k < 5; k++) {
            #pragma unroll
            for (int k2 = k; k2 < 5; k2++) d[p++] += w[k] * w[k2];
        }
        #pragma unroll
        for (int k = 0; k < 5; k++) d[15 + k] += b * w[k];
        d[20] += b * b;
    }
    #pragma unroll
    for (int i = 0; i < 21; i++) {
        #pragma unroll
        for (int off = 32; off; off >>= 1) d[i] += __shfl_down(d[i], off);
    }
    if (threadIdx.x == 0) {
        const float* H1 = a.H + l * 20;
        const float* H2 = H1 + 5;
        float sq = (float)a.E[l] * d[20];
        #pragma unroll
        for (int k = 0; k < 5; k++) sq += 2.f * d[15 + k] * H1[k];
        int p = 0;
        #pragma unroll
        for (int k = 0; k < 5; k++) {
            #pragma unroll
            for (int k2 = k; k2 < 5; k2++) {
                sq += ((k == k2) ? 1.f : 2.f) * d[p] * H2[p];
                p++;
            }
        }
        a.sq[l] = sq;
    }
}

// ---------------------------------------------------------------------------
// coop_conv_k (L1-L4): one block per node (unchanged).
// ---------------------------------------------------------------------------
template<int CI, int CO>
__global__ __launch_bounds__(256) void coop_conv_k(
    const int* __restrict__ rp, const int* __restrict__ eid,
    const int* __restrict__ src, const float* __restrict__ eattr,
    const float* __restrict__ w1, const float* __restrict__ b1,
    const float* __restrict__ w2, const float* __restrict__ b2,
    const float* __restrict__ root, const float* __restrict__ bias,
    const float* __restrict__ x, float* __restrict__ y)
{
    constexpr int CH   = 48;
    constexpr int CICO = CI * CO;
    static_assert(6 * CI <= 256, "phase-A lanes");
    __shared__ float w1s[20];
    __shared__ int   eb[CH], svb[CH];
    __shared__ float hb[CH * 6];
    __shared__ float xs[CH * CI];
    __shared__ float S[6 * CI];

    int t = threadIdx.x;
    int v = blockIdx.x;
    if (t < 20) w1s[t] = (t < 15) ? w1[t] : b1[t - 15];
    int r0 = rp[v], r1 = rp[v + 1];
    int d  = r1 - r0;
    float acc = 0.f;

    for (int c0 = r0; c0 < r1; c0 += CH) {
        int cn = min(CH, r1 - c0);
        if (t < cn) {
            int e = eid[c0 + t];
            eb[t]  = e;
            svb[t] = src[e];
            hb[t * 6] = 1.f;
        }
        __syncthreads();
        if (t < cn * 5) {
            int j = t / 5, k = t % 5;
            int e = eb[j];
            float e0 = eattr[e * 3], e1 = eattr[e * 3 + 1], e2 = eattr[e * 3 + 2];
            hb[j * 6 + 1 + k] =
                tanhf(e0 * w1s[k] + e1 * w1s[5 + k] + e2 * w1s[10 + k] + w1s[15 + k]);
        }
        for (int u = t; u < cn * CI; u += 256)
            xs[u] = x[(size_t)svb[u / CI] * CI + (u % CI)];
        __syncthreads();
        if (t < 6 * CI) {
            int i = t / 6, k6 = t % 6;
            for (int j = 0; j < cn; j++)
                acc += hb[j * 6 + k6] * xs[j * CI + i];
        }
        __syncthreads();
    }

    if (t < 6 * CI) S[t] = acc;
    __syncthreads();

    if (t < CO) {
        float m = 0.f;
        for (int i = 0; i < CI; i++) {
            m += b2[i * CO + t] * S[i * 6];
            #pragma unroll
            for (int k = 0; k < 5; k++)
                m += w2[k * CICO + i * CO + t] * S[i * 6 + 1 + k];
        }
        m /= fmaxf((float)d, 1.f);
        for (int i = 0; i < CI; i++)
            m += x[(size_t)v * CI + i] * root[i * CO + t];
        y[(size_t)v * CO + t] = m + bias[t];
    }
}

// ---------------------------------------------------------------------------
// pool_k (unchanged).
// ---------------------------------------------------------------------------
template<int CO>
__global__ __launch_bounds__(256) void pool_k(
    int NN,
    const int* __restrict__ crp, const int* __restrict__ cnid,
    const float* __restrict__ y, const float* __restrict__ pos,
    float* __restrict__ xn, float* __restrict__ pn)
{
    int t = blockIdx.x * 256 + threadIdx.x;
    if (t >= NN * (CO + 3)) return;
    int c = t / (CO + 3), o = t % (CO + 3);
    int r0 = crp[c], r1 = crp[c + 1];
    int d = r1 - r0;
    if (o < CO) {
        float m = -INFINITY;
        for (int j = r0; j < r1; j++)
            m = fmaxf(m, y[(size_t)cnid[j] * CO + o]);
        if (d == 0 || !isfinite(m)) m = 0.f;
        xn[c * (CO + 3) + o] = m;
    } else {
        int k = o - CO;
        float sum = 0.f;
        for (int j = r0; j < r1; j++)
            sum += pos[cnid[j] * 3 + k];
        float pm = sum / fmaxf((float)d, 1.f);
        xn[c * (CO + 3) + CO + k] = pm;
        pn[c * 3 + k] = pm;
    }
}

// ---------------------------------------------------------------------------
// fc_k (unchanged).
// ---------------------------------------------------------------------------
__global__ __launch_bounds__(128) void fc_k(
    const float* __restrict__ x5,
    const float* __restrict__ fc_w, const float* __restrict__ fc_b,
    const float* __restrict__ sq, float* __restrict__ out)
{
    __shared__ float feat[8 * 376];
    __shared__ float logit[80];
    __shared__ float roff[8];
    for (int t = threadIdx.x; t < 8 * 376; t += 128) feat[t] = x5[t];
    __syncthreads();
    int t = threadIdx.x;
    if (t < 80) {
        int b = t / 10, j = t % 10;
        float acc = fc_b[j];
        for (int k = 0; k < 376; k++) acc += feat[b * 376 + k] * fc_w[k * 10 + j];
        logit[t] = acc;
    }
    __syncthreads();
    if (t < 8) {
        float m = -1e30f;
        for (int j = 0; j < 10; j++) m = fmaxf(m, logit[t * 10 + j]);
        float ssum = 0.f;
        for (int j = 0; j < 10; j++) ssum += expf(logit[t * 10 + j] - m);
        roff[t] = m + logf(ssum);
    }
    __syncthreads();
    if (t < 80) out[t] = logit[t] - roff[t / 10];
    if (t == 0) {
        float closs = 0.f;
        closs += sq[0] * (1.0f / 12582912.0f);
        closs += sq[1] * (1.0f / 78643200.0f);
        closs += sq[2] * (1.0f / 42205184.0f);
        closs += sq[3] * (1.0f / 18284544.0f);
        closs += sq[4] * (1.0f / 7028736.0f);
        out[80] = closs;
    }
}

// ---------------------------------------------------------------------------

extern "C" void kernel_launch(void* const* d_in, const int* in_sizes, int n_in,
                              void* d_out, int out_size, void* d_ws, size_t ws_size,
                              hipStream_t stream)
{
    static const int NSa[6] = {65536, 16384, 4096, 1024, 256, 64};
    static const int ESa[5] = {1048576, 262144, 65536, 16384, 4096};
    static const int COa[5] = {12, 20, 28, 36, 44};
    static const int CIa[5] = {1, 15, 23, 31, 39};

    const float* x0   = (const float*)d_in[0];
    const float* pos0 = (const float*)d_in[1];

    // ---- workspace layout (words), ~50 MB total ----
    int* wsw = (int*)d_ws;
    size_t off = 0;
    auto alw = [&](size_t n) -> size_t {
        size_t p = off; off += (n + 63) & ~(size_t)63; return p;
    };
    size_t degO[5], cdegO[5];
    for (int l = 1; l < 5; l++) degO[l]  = alw(NSa[l]);
    for (int l = 0; l < 5; l++) cdegO[l] = alw(NSa[l + 1]);
    size_t HO = alw(100);
    size_t zeroWords = off;                               // zero-init to here
    size_t rpO[5], crpO[5], eidO[5], cnidO[5];
    for (int l = 1; l < 5; l++) rpO[l]  = alw(NSa[l] + 1);
    for (int l = 0; l < 5; l++) crpO[l] = alw(NSa[l + 1] + 1);
    for (int l = 1; l < 5; l++) eidO[l] = alw(ESa[l]);
    for (int l = 0; l < 5; l++) cnidO[l] = alw(NSa[l]);
    size_t tsO  = alw(64);
    size_t toO  = alw(64);
    size_t MO   = alw((size_t)TILES0 * NB0);
    size_t M2O  = alw((size_t)TILES0 * NB0);
    size_t ctO  = alw(NB0);
    size_t bsO  = alw(NB0 + 1);
    size_t keysO = alw((size_t)ESa[0]);
    size_t payO = alw((size_t)ESa[0] * 8);                // 32B records
    size_t yO   = alw((size_t)65536 * 12);
    size_t sqO  = alw(8);
    size_t xnO[5], pnO[5];
    for (int l = 0; l < 5; l++) xnO[l] = alw((size_t)NSa[l + 1] * (COa[l] + 3));
    for (int l = 0; l < 5; l++) pnO[l] = alw((size_t)NSa[l + 1] * 3);

    hipMemsetAsync(d_ws, 0, zeroWords * 4, stream);

    // ---- segs 1-9 descriptor (edge segs 1-4 + cluster segs 0-4) ----
    SegArgs sa{};
    int nseg = 0;
    for (int l = 1; l < 5; l++) {
        sa.idx[nseg] = (const int*)d_in[3 + 10 * l];
        sa.cnt[nseg] = wsw + degO[l];
        sa.rp [nseg] = wsw + rpO[l];
        sa.out[nseg] = wsw + eidO[l];
        sa.n  [nseg] = ESa[l];
        sa.nb [nseg] = NSa[l];
        nseg++;
    }
    for (int l = 0; l < 5; l++) {
        sa.idx[nseg] = (const int*)d_in[5 + 10 * l];
        sa.cnt[nseg] = wsw + cdegO[l];
        sa.rp [nseg] = wsw + crpO[l];
        sa.out[nseg] = wsw + cnidO[l];
        sa.n  [nseg] = NSa[l];
        sa.nb [nseg] = NSa[l + 1];
        nseg++;
    }
    ScanAux sx{};
    int tiles = 0, btiles = 0;
    for (int s = 0; s < nseg; s++) {
        int lg = 31 - __builtin_clz(sa.nb[s]);
        sa.shift[s] = lg - 3;
        sa.tstart[s] = tiles;
        tiles += (sa.n[s] + 255) / 256;
        sx.sstart[s] = btiles;
        btiles += (sa.nb[s] + 4095) / 4096;
    }
    for (int s = nseg; s <= 10; s++) {
        sa.tstart[s] = tiles;
        sx.sstart[s] = btiles;
        if (s < 10) {
            sa.idx[s] = sa.idx[nseg - 1]; sa.cnt[s] = sa.cnt[nseg - 1];
            sa.rp[s] = sa.rp[nseg - 1];   sa.out[s] = sa.out[nseg - 1];
            sa.n[s] = 0; sa.nb[s] = 8; sa.shift[s] = 0;
        }
    }
    sx.T = btiles;
    sx.tilesum = wsw + tsO;
    sx.tileoff = wsw + toO;

    int*    keys = wsw + keysO;
    float4* pay2 = (float4*)(wsw + payO);
    float*  Hp   = (float*)(wsw + HO);

    // ---- seg0 deterministic radix build + fused h/stats ----
    cnt0_k   <<<TILES0, 256, 0, stream>>>((const int*)d_in[3], wsw + MO);
    colscan_k<<<NB0, 256, 0, stream>>>(wsw + MO, wsw + M2O, wsw + ctO);
    bktscan_k<<<1, NB0, 0, stream>>>(wsw + ctO, wsw + bsO);
    part0_k  <<<TILES0, 256, 0, stream>>>(
        (const int*)d_in[2], (const int*)d_in[3], (const float*)d_in[4],
        x0, wsw + M2O, wsw + bsO, keys, pay2,
        (const float*)d_in[6], (const float*)d_in[7], Hp);

    // ---- segs 1-9 atomic build ----
    hist_all_k   <<<tiles * NBUCK, 256, 0, stream>>>(sa);
    scanA_k      <<<btiles, 256, 0, stream>>>(sa, sx);
    scanB_k      <<<1, 64, 0, stream>>>(sa, sx);
    scanC_k      <<<btiles, 256, 0, stream>>>(sa, sx);
    scatter_all_k<<<tiles * NBUCK, 256, 0, stream>>>(sa);

    // ---- closs statistics: hstats for levels 1-4 only ----
    HArgs ha{};
    int bs = 0;
    ha.bstart[0] = 0;
    ha.eattr[0] = (const float*)d_in[4];
    ha.w1[0] = (const float*)d_in[6];
    ha.b1[0] = (const float*)d_in[7];
    ha.E[0] = 0;
    for (int l = 1; l < 5; l++) {
        ha.eattr[l] = (const float*)d_in[4 + 10 * l];
        ha.w1[l]    = (const float*)d_in[6 + 10 * l];
        ha.b1[l]    = (const float*)d_in[7 + 10 * l];
        ha.E[l]     = ESa[l];
        ha.bstart[l] = bs;
        bs += (ESa[l] + 256 * 32 - 1) / (256 * 32);
    }
    ha.bstart[5] = bs;
    ha.H = Hp;
    hstats_k<<<bs, 256, 0, stream>>>(ha);

    WArgs wa{};
    for (int l = 0; l < 5; l++) {
        wa.w2[l]   = (const float*)d_in[8 + 10 * l];
        wa.b2[l]   = (const float*)d_in[9 + 10 * l];
        wa.cico[l] = CIa[l] * COa[l];
        wa.E[l]    = ESa[l];
    }
    wa.H  = Hp;
    wa.sq = (float*)(wsw + sqO);
    wstats_k<<<5, 64, 0, stream>>>(wa);

    float* yb = (float*)(wsw + yO);

    // ---- level 0: fused in-LDS CSR + register accumulation conv ----
    conv0c_k<<<NB0, 256, 0, stream>>>(
        keys, pay2, wsw + bsO,
        (const float*)d_in[8], (const float*)d_in[9],
        (const float*)d_in[10], (const float*)d_in[11], x0, yb);
    pool_k<12><<<(NSa[1] * 15 + 255) / 256, 256, 0, stream>>>(
        NSa[1], wsw + crpO[0], wsw + cnidO[0], yb, pos0,
        (float*)(wsw + xnO[0]), (float*)(wsw + pnO[0]));

    // ---- levels 1-4 ----
#define LVLC(l, CI_, CO_) do {                                                 \
    const float* xin   = (const float*)(wsw + xnO[(l) - 1]);                   \
    const float* posin = (const float*)(wsw + pnO[(l) - 1]);                   \
    int N = NSa[(l)], NN = NSa[(l) + 1];                                       \
    coop_conv_k<CI_, CO_><<<N, 256, 0, stream>>>(                              \
        wsw + rpO[(l)], wsw + eidO[(l)],                                       \
        (const int*)d_in[2 + 10 * (l)], (const float*)d_in[4 + 10 * (l)],      \
        (const float*)d_in[6 + 10 * (l)], (const float*)d_in[7 + 10 * (l)],    \
        (const float*)d_in[8 + 10 * (l)], (const float*)d_in[9 + 10 * (l)],    \
        (const float*)d_in[10 + 10 * (l)], (const float*)d_in[11 + 10 * (l)],  \
        xin, yb);                                                              \
    pool_k<CO_><<<(NN * ((CO_) + 3) + 255) / 256, 256, 0, stream>>>(           \
        NN, wsw + crpO[(l)], wsw + cnidO[(l)], yb, posin,                      \
        (float*)(wsw + xnO[(l)]), (float*)(wsw + pnO[(l)]));                   \
} while (0)

    LVLC(1, 15, 20);
    LVLC(2, 23, 28);
    LVLC(3, 31, 36);
    LVLC(4, 39, 44);
#undef LVLC

    fc_k<<<1, 128, 0, stream>>>((const float*)(wsw + xnO[4]),
                                (const float*)d_in[52], (const float*)d_in[53],
                                (const float*)(wsw + sqO), (float*)d_out);
}

// Round 13
// 460.845 us; speedup vs baseline: 1.0512x; 1.0512x over previous
//
#include <hip/hip_runtime.h>
#include <hip/hip_fp16.h>
#include <math.h>

// ---------------------------------------------------------------------------
// Net_37512244363273: 5-level edge-conditioned graph conv + voxel pooling + FC
// Round 13: part0 was WRITE-transaction bound (80 MB for 40 MB payload;
// model: payload + T*NB0*64B cross-XCD boundary lines, verified by the
// round-11/12 T sweep). Fix: 16 B records (x fp32, h0..h4 fp16-packed, dst
// key in top 16 bits of .w -- no separate keys array) + T=256 tiles so ~8
// consecutive records/bucket/block merge into full lines in the writer's L2.
// Expected writes ~24 MB. conv0c unpacks fp16 h at accumulate. Everything
// else unchanged from round 12. Output: 80 log_softmax + closs = 81 floats.
// ---------------------------------------------------------------------------

#define NBUCK 8
#define TILES0 256                 // seg0 tiles (4096 edges each)
#define NB0    512                 // seg0 buckets (dst>>7, 128 nodes each)
#define IDXCAP 3072                // per-bucket index capacity (mean 2048)

// ---- segment descriptor for CSR builds (segs 1-9: edge 1-4 + cluster 0-4) --
struct SegArgs {
    const int* idx[10];
    int*       cnt[10];
    int*       rp [10];
    int*       out[10];
    int        n  [10];
    int        nb [10];
    int        shift[10];
    int        tstart[11];
};

struct ScanAux {
    int* tilesum;
    int* tileoff;
    int  sstart[11];
    int  T;
};

// XCD-bucketed histogram (per-element global atomics; small segs only).
__global__ __launch_bounds__(256) void hist_all_k(SegArgs a) {
    int B = blockIdx.x;
    int bucket = B % NBUCK;
    int T = B / NBUCK;
    int s = 0;
    while (s < 9 && T >= a.tstart[s + 1]) s++;
    int i = (T - a.tstart[s]) * 256 + threadIdx.x;
    if (i >= a.n[s]) return;
    int d = a.idx[s][i];
    if ((d >> a.shift[s]) != bucket) return;
    atomicAdd(&a.cnt[s][d], 1);
}

// 3-phase hierarchical scan over segs 1-9 cnt arrays.
__global__ __launch_bounds__(256) void scanA_k(SegArgs a, ScanAux x) {
    int b = blockIdx.x;
    int s = 0;
    while (s < 9 && b >= x.sstart[s + 1]) s++;
    int tloc = b - x.sstart[s];
    int nb = a.nb[s];
    const int* cnt = a.cnt[s];
    int i0 = tloc * 4096 + threadIdx.x * 16;
    int sum = 0;
    #pragma unroll
    for (int k = 0; k < 16; k++) {
        int i = i0 + k;
        if (i < nb) sum += cnt[i];
    }
    #pragma unroll
    for (int o = 32; o; o >>= 1) sum += __shfl_down(sum, o);
    __shared__ int red[4];
    if ((threadIdx.x & 63) == 0) red[threadIdx.x >> 6] = sum;
    __syncthreads();
    if (threadIdx.x == 0)
        x.tilesum[b] = red[0] + red[1] + red[2] + red[3];
}

__global__ __launch_bounds__(64) void scanB_k(SegArgs a, ScanAux x) {
    int lane = threadIdx.x;
    int orig = (lane < x.T) ? x.tilesum[lane] : 0;
    int val = orig;
    #pragma unroll
    for (int d = 1; d < 64; d <<= 1) {
        int v = __shfl_up(val, d);
        if (lane >= d) val += v;
    }
    int excl = val - orig;
    int s = 0;
    while (s < 9 && lane >= x.sstart[s + 1]) s++;
    int segExcl = __shfl(excl, x.sstart[s]);
    if (lane < x.T) {
        x.tileoff[lane] = excl - segExcl;
        if (lane == x.sstart[s + 1] - 1)
            a.rp[s][a.nb[s]] = val - segExcl;
    }
}

__global__ __launch_bounds__(256) void scanC_k(SegArgs a, ScanAux x) {
    int b = blockIdx.x;
    int s = 0;
    while (s < 9 && b >= x.sstart[s + 1]) s++;
    int tloc = b - x.sstart[s];
    int nb = a.nb[s];
    const int* cnt = a.cnt[s];
    int* rp = a.rp[s];
    int i0 = tloc * 4096 + threadIdx.x * 16;
    int v[16];
    int sum = 0;
    #pragma unroll
    for (int k = 0; k < 16; k++) {
        int i = i0 + k;
        v[k] = (i < nb) ? cnt[i] : 0;
        sum += v[k];
    }
    __shared__ int sc[256];
    int acc = sum;
    sc[threadIdx.x] = acc;
    __syncthreads();
    for (int d = 1; d < 256; d <<= 1) {
        int t2 = (threadIdx.x >= d) ? sc[threadIdx.x - d] : 0;
        __syncthreads();
        acc += t2;
        sc[threadIdx.x] = acc;
        __syncthreads();
    }
    int running = x.tileoff[b] + (acc - sum);
    #pragma unroll
    for (int k = 0; k < 16; k++) {
        int i = i0 + k;
        if (i < nb) rp[i] = running;
        running += v[k];
    }
}

// XCD-bucketed countdown-scatter (small segs only).
__global__ __launch_bounds__(256) void scatter_all_k(SegArgs a) {
    int B = blockIdx.x;
    int bucket = B % NBUCK;
    int T = B / NBUCK;
    int s = 0;
    while (s < 9 && T >= a.tstart[s + 1]) s++;
    int i = (T - a.tstart[s]) * 256 + threadIdx.x;
    if (i >= a.n[s]) return;
    int d = a.idx[s][i];
    if ((d >> a.shift[s]) != bucket) return;
    int p = atomicSub(&a.cnt[s][d], 1) - 1;
    a.out[s][a.rp[s][d] + p] = i;
}

// ---------------------------------------------------------------------------
// Seg-0 pipeline: deterministic 512-bucket partition (fused h + L0 stats,
// 16 B fp16-packed records), then per-bucket in-LDS CSR + register conv.
// ---------------------------------------------------------------------------
__global__ __launch_bounds__(256) void cnt0_k(
    const int* __restrict__ dst, int* __restrict__ M)
{
    __shared__ int h[NB0];
    int t = threadIdx.x;
    for (int u = t; u < NB0; u += 256) h[u] = 0;
    __syncthreads();
    int base = blockIdx.x * 4096 + t;
    #pragma unroll
    for (int it = 0; it < 16; it++)
        atomicAdd(&h[dst[base + it * 256] >> 7], 1);      // LDS
    __syncthreads();
    for (int u = t; u < NB0; u += 256) M[(size_t)blockIdx.x * NB0 + u] = h[u];
}

// per-bucket exclusive scan over the 256 tiles.
__global__ __launch_bounds__(256) void colscan_k(
    const int* __restrict__ M, int* __restrict__ M2, int* __restrict__ colTotal)
{
    int b = blockIdx.x, t = threadIdx.x;
    int v = M[(size_t)t * NB0 + b];
    __shared__ int sc[256];
    sc[t] = v;
    __syncthreads();
    for (int d = 1; d < 256; d <<= 1) {
        int u = (t >= d) ? sc[t - d] : 0;
        __syncthreads();
        sc[t] += u;
        __syncthreads();
    }
    M2[(size_t)t * NB0 + b] = sc[t] - v;
    if (t == 255) colTotal[b] = sc[255];
}

__global__ __launch_bounds__(512) void bktscan_k(
    const int* __restrict__ colTotal, int* __restrict__ bucketStart)
{
    int t = threadIdx.x;
    int v = colTotal[t];
    __shared__ int sc[NB0];
    sc[t] = v;
    __syncthreads();
    for (int d = 1; d < NB0; d <<= 1) {
        int u = (t >= d) ? sc[t - d] : 0;
        __syncthreads();
        sc[t] += u;
        __syncthreads();
    }
    bucketStart[t] = sc[t] - v;
    if (t == NB0 - 1) bucketStart[NB0] = sc[NB0 - 1];
}

// partition + fused h/tanh + level-0 h-stats. 16 B record:
//   .x = x_src (fp32), .y = half2(h0,h1), .z = half2(h2,h3),
//   .w = (dst << 16) | half(h4)      [dst < 65536]
__global__ __launch_bounds__(256) void part0_k(
    const int* __restrict__ src, const int* __restrict__ dst,
    const float* __restrict__ ea, const float* __restrict__ x0,
    const int* __restrict__ M2, const int* __restrict__ bucketStart,
    float4* __restrict__ pay2,
    const float* __restrict__ w1, const float* __restrict__ b1,
    float* __restrict__ H0)
{
    __shared__ int cur[NB0];
    __shared__ float w1s[15], b1s[5];
    __shared__ float red[4][20];
    int t = threadIdx.x;
    for (int u = t; u < NB0; u += 256)
        cur[u] = bucketStart[u] + M2[(size_t)blockIdx.x * NB0 + u];
    if (t < 15) w1s[t] = w1[t];
    if (t >= 32 && t < 37) b1s[t - 32] = b1[t - 32];
    __syncthreads();

    float acc[20];
    #pragma unroll
    for (int i = 0; i < 20; i++) acc[i] = 0.f;

    int base = blockIdx.x * 4096 + t;
    #pragma unroll 4
    for (int it = 0; it < 16; it++) {
        int i = base + it * 256;
        int d = dst[i];
        float e0 = ea[i * 3], e1 = ea[i * 3 + 1], e2 = ea[i * 3 + 2];
        float h[5];
        #pragma unroll
        for (int k = 0; k < 5; k++)
            h[k] = tanhf(e0 * w1s[k] + e1 * w1s[5 + k] + e2 * w1s[10 + k] + b1s[k]);
        int p = 5;
        #pragma unroll
        for (int k = 0; k < 5; k++) {
            acc[k] += h[k];
            #pragma unroll
            for (int k2 = k; k2 < 5; k2++) acc[p++] += h[k] * h[k2];
        }
        float xv = x0[src[i]];
        union HU { __half2 h2; float f; } p01, p23;
        p01.h2 = __floats2half2_rn(h[0], h[1]);
        p23.h2 = __floats2half2_rn(h[2], h[3]);
        unsigned wbits = ((unsigned)d << 16) |
                         (unsigned)__half_as_ushort(__float2half_rn(h[4]));
        int ps = atomicAdd(&cur[d >> 7], 1);              // LDS
        pay2[ps] = make_float4(xv, p01.f, p23.f, __uint_as_float(wbits));
    }

    // level-0 h-stat reduction: wave shfl -> LDS -> 20 atomics per block
    int wid = t >> 6, lane = t & 63;
    #pragma unroll
    for (int v = 0; v < 20; v++) {
        float s = acc[v];
        #pragma unroll
        for (int o = 32; o; o >>= 1) s += __shfl_down(s, o);
        if (lane == 0) red[wid][v] = s;
    }
    __syncthreads();
    if (t < 20)
        atomicAdd(&H0[t], red[0][t] + red[1][t] + red[2][t] + red[3][t]);
}

// conv0c: one block per 128-node bucket. In-LDS CSR of record indices
// (2 low-contention LDS atomics/record), then per-node register sums with
// fp16 h unpacking.
__global__ __launch_bounds__(256) void conv0c_k(
    const float4* __restrict__ pay2, const int* __restrict__ bucketStart,
    const float* __restrict__ w2, const float* __restrict__ b2,
    const float* __restrict__ root, const float* __restrict__ bias,
    const float* __restrict__ x, float* __restrict__ y)
{
    __shared__ float w2s[60], b2s[12], roots[12], biass[12];
    __shared__ int hist[128], st[128], cur[128];
    __shared__ int idxL[IDXCAP];
    int t = threadIdx.x;
    if (t < 60) w2s[t] = w2[t];
    else if (t >= 64  && t < 76)  b2s[t - 64]    = b2[t - 64];
    else if (t >= 128 && t < 140) roots[t - 128] = root[t - 128];
    else if (t >= 192 && t < 204) biass[t - 192] = bias[t - 192];
    if (t < 128) hist[t] = 0;
    __syncthreads();

    int b = blockIdx.x;
    int lo = bucketStart[b], hi = bucketStart[b + 1];
    int bin0 = b << 7;
    const float* payw = (const float*)pay2;               // .w component access
    for (int j = lo + t; j < hi; j += 256) {
        int rel = (int)(__float_as_uint(payw[4 * j + 3]) >> 16) - bin0;
        atomicAdd(&hist[rel], 1);                         // LDS
    }
    __syncthreads();
    if (t < 128) st[t] = hist[t];
    __syncthreads();
    for (int d = 1; d < 128; d <<= 1) {
        int u = (t < 128 && t >= d) ? st[t - d] : 0;
        __syncthreads();
        if (t < 128) st[t] += u;
        __syncthreads();
    }
    if (t < 128) cur[t] = st[t] - hist[t];                // exclusive
    __syncthreads();
    for (int j = lo + t; j < hi; j += 256) {
        int rel = (int)(__float_as_uint(payw[4 * j + 3]) >> 16) - bin0;
        int p = atomicAdd(&cur[rel], 1);                  // LDS
        idxL[p] = j;
    }
    __syncthreads();

    if (t < 128) {
        int v = bin0 + t;
        int deg = hist[t];
        int s0 = st[t] - deg;
        float S0 = 0.f, S1 = 0.f, S2 = 0.f, S3 = 0.f, S4 = 0.f, S5 = 0.f;
        for (int jj = s0; jj < s0 + deg; jj++) {
            float4 R = pay2[idxL[jj]];
            union HU { float f; __half2 h2; } a01, a23;
            a01.f = R.y; a23.f = R.z;
            unsigned wbits = __float_as_uint(R.w);
            float xv = R.x;
            S0 += xv;
            S1 += __low2float(a01.h2)  * xv;
            S2 += __high2float(a01.h2) * xv;
            S3 += __low2float(a23.h2)  * xv;
            S4 += __high2float(a23.h2) * xv;
            S5 += __half2float(__ushort_as_half((unsigned short)(wbits & 0xffffu))) * xv;
        }
        float inv = 1.f / fmaxf((float)deg, 1.f);
        float xv = x[v];
        #pragma unroll
        for (int o = 0; o < 12; o++) {
            float msg = b2s[o] * S0 + w2s[o] * S1 + w2s[12 + o] * S2 +
                        w2s[24 + o] * S3 + w2s[36 + o] * S4 + w2s[48 + o] * S5;
            y[v * 12 + o] = msg * inv + xv * roots[o] + biass[o];
        }
    }
}

// ---------------------------------------------------------------------------
// hstats (levels 1-4 only) / wstats: closs via h-statistics.
// ---------------------------------------------------------------------------
struct HArgs {
    const float* eattr[5];
    const float* w1[5];
    const float* b1[5];
    float*       H;
    int          E[5];
    int          bstart[6];
};

__global__ __launch_bounds__(256) void hstats_k(HArgs a) {
    const int K = 32;
    int b = blockIdx.x, l = 0;
    while (l < 4 && b >= a.bstart[l + 1]) l++;
    int bloc = b - a.bstart[l];
    const float* ea = a.eattr[l];
    float w1r[15], b1r[5];
    #pragma unroll
    for (int i = 0; i < 15; i++) w1r[i] = a.w1[l][i];
    #pragma unroll
    for (int i = 0; i < 5; i++)  b1r[i] = a.b1[l][i];
    float acc[20];
    #pragma unroll
    for (int i = 0; i < 20; i++) acc[i] = 0.f;
    int base = bloc * 256 * K + threadIdx.x;
    for (int it = 0; it < K; it++) {
        int e = base + it * 256;
        if (e < a.E[l]) {
            float e0 = ea[e * 3], e1 = ea[e * 3 + 1], e2 = ea[e * 3 + 2];
            float h[5];
            #pragma unroll
            for (int k = 0; k < 5; k++)
                h[k] = tanhf(e0 * w1r[k] + e1 * w1r[5 + k] + e2 * w1r[10 + k] + b1r[k]);
            int p = 5;
            #pragma unroll
            for (int k = 0; k < 5; k++) {
                acc[k] += h[k];
                #pragma unroll
                for (int k2 = k; k2 < 5; k2++) acc[p++] += h[k] * h[k2];
            }
        }
    }
    __shared__ float red[4][20];
    int wid = threadIdx.x >> 6, lane = threadIdx.x & 63;
    #pragma unroll
    for (int v = 0; v < 20; v++) {
        float s = acc[v];
        #pragma unroll
        for (int off = 32; off; off >>= 1) s += __shfl_down(s, off);
        if (lane == 0) red[wid][v] = s;
    }
    __syncthreads();
    if (threadIdx.x < 20) {
        float s = red[0][threadIdx.x] + red[1][threadIdx.x] +
                  red[2][threadIdx.x] + red[3][threadIdx.x];
        atomicAdd(&a.H[l * 20 + threadIdx.x], s);
    }
}

struct WArgs {
    const float* w2[5];
    const float* b2[5];
    const float* H;
    float*       sq;
    int          cico[5];
    int          E[5];
};

__global__ __launch_bounds__(64) void wstats_k(WArgs a) {
    int l = blockIdx.x;
    const float* w2 = a.w2[l];
    const float* b2 = a.b2[l];
    int cico = a.cico[l];
    float d[21];
    #pragma unroll
    for (int i = 0; i < 21; i++) d[i] = 0.f;
    for (int u = threadIdx.x; u < cico; u += 64) {
        float b = b2[u];
        float w[5];
        #pragma unroll
        for (int k = 0; k < 5; k++) w[k] = w2[k * cico + u];
        int p = 0;
        #pragma unroll
        for (int k = 0; k < 5; k++) {
            #pragma unroll
            for (int k2 = k; k2 < 5; k2++) d[p++] += w[k] * w[k2];
        }
        #pragma unroll
        for (int k = 0; k < 5; k++) d[15 + k] += b * w[k];
        d[20] += b * b;
    }
    #pragma unroll
    for (int i = 0; i < 21; i++) {
        #pragma unroll
        for (int off = 32; off; off >>= 1) d[i] += __shfl_down(d[i], off);
    }
    if (threadIdx.x == 0) {
        const float* H1 = a.H + l * 20;
        const float* H2 = H1 + 5;
        float sq = (float)a.E[l] * d[20];
        #pragma unroll
        for (int k = 0; k < 5; k++) sq += 2.f * d[15 + k] * H1[k];
        int p = 0;
        #pragma unroll
        for (int k = 0; k < 5; k++) {
            #pragma unroll
            for (int k2 = k; k2 < 5; k2++) {
                sq += ((k == k2) ? 1.f : 2.f) * d[p] * H2[p];
                p++;
            }
        }
        a.sq[l] = sq;
    }
}

// ---------------------------------------------------------------------------
// coop_conv_k (L1-L4): one block per node (unchanged).
// ---------------------------------------------------------------------------
template<int CI, int CO>
__global__ __launch_bounds__(256) void coop_conv_k(
    const int* __restrict__ rp, const int* __restrict__ eid,
    const int* __restrict__ src, const float* __restrict__ eattr,
    const float* __restrict__ w1, const float* __restrict__ b1,
    const float* __restrict__ w2, const float* __restrict__ b2,
    const float* __restrict__ root, const float* __restrict__ bias,
    const float* __restrict__ x, float* __restrict__ y)
{
    constexpr int CH   = 48;
    constexpr int CICO = CI * CO;
    static_assert(6 * CI <= 256, "phase-A lanes");
    __shared__ float w1s[20];
    __shared__ int   eb[CH], svb[CH];
    __shared__ float hb[CH * 6];
    __shared__ float xs[CH * CI];
    __shared__ float S[6 * CI];

    int t = threadIdx.x;
    int v = blockIdx.x;
    if (t < 20) w1s[t] = (t < 15) ? w1[t] : b1[t - 15];
    int r0 = rp[v], r1 = rp[v + 1];
    int d  = r1 - r0;
    float acc = 0.f;

    for (int c0 = r0; c0 < r1; c0 += CH) {
        int cn = min(CH, r1 - c0);
        if (t < cn) {
            int e = eid[c0 + t];
            eb[t]  = e;
            svb[t] = src[e];
            hb[t * 6] = 1.f;
        }
        __syncthreads();
        if (t < cn * 5) {
            int j = t / 5, k = t % 5;
            int e = eb[j];
            float e0 = eattr[e * 3], e1 = eattr[e * 3 + 1], e2 = eattr[e * 3 + 2];
            hb[j * 6 + 1 + k] =
                tanhf(e0 * w1s[k] + e1 * w1s[5 + k] + e2 * w1s[10 + k] + w1s[15 + k]);
        }
        for (int u = t; u < cn * CI; u += 256)
            xs[u] = x[(size_t)svb[u / CI] * CI + (u % CI)];
        __syncthreads();
        if (t < 6 * CI) {
            int i = t / 6, k6 = t % 6;
            for (int j = 0; j < cn; j++)
                acc += hb[j * 6 + k6] * xs[j * CI + i];
        }
        __syncthreads();
    }

    if (t < 6 * CI) S[t] = acc;
    __syncthreads();

    if (t < CO) {
        float m = 0.f;
        for (int i = 0; i < CI; i++) {
            m += b2[i * CO + t] * S[i * 6];
            #pragma unroll
            for (int k = 0; k < 5; k++)
                m += w2[k * CICO + i * CO + t] * S[i * 6 + 1 + k];
        }
        m /= fmaxf((float)d, 1.f);
        for (int i = 0; i < CI; i++)
            m += x[(size_t)v * CI + i] * root[i * CO + t];
        y[(size_t)v * CO + t] = m + bias[t];
    }
}

// ---------------------------------------------------------------------------
// pool_k (unchanged).
// ---------------------------------------------------------------------------
template<int CO>
__global__ __launch_bounds__(256) void pool_k(
    int NN,
    const int* __restrict__ crp, const int* __restrict__ cnid,
    const float* __restrict__ y, const float* __restrict__ pos,
    float* __restrict__ xn, float* __restrict__ pn)
{
    int t = blockIdx.x * 256 + threadIdx.x;
    if (t >= NN * (CO + 3)) return;
    int c = t / (CO + 3), o = t % (CO + 3);
    int r0 = crp[c], r1 = crp[c + 1];
    int d = r1 - r0;
    if (o < CO) {
        float m = -INFINITY;
        for (int j = r0; j < r1; j++)
            m = fmaxf(m, y[(size_t)cnid[j] * CO + o]);
        if (d == 0 || !isfinite(m)) m = 0.f;
        xn[c * (CO + 3) + o] = m;
    } else {
        int k = o - CO;
        float sum = 0.f;
        for (int j = r0; j < r1; j++)
            sum += pos[cnid[j] * 3 + k];
        float pm = sum / fmaxf((float)d, 1.f);
        xn[c * (CO + 3) + CO + k] = pm;
        pn[c * 3 + k] = pm;
    }
}

// ---------------------------------------------------------------------------
// fc_k (unchanged).
// ---------------------------------------------------------------------------
__global__ __launch_bounds__(128) void fc_k(
    const float* __restrict__ x5,
    const float* __restrict__ fc_w, const float* __restrict__ fc_b,
    const float* __restrict__ sq, float* __restrict__ out)
{
    __shared__ float feat[8 * 376];
    __shared__ float logit[80];
    __shared__ float roff[8];
    for (int t = threadIdx.x; t < 8 * 376; t += 128) feat[t] = x5[t];
    __syncthreads();
    int t = threadIdx.x;
    if (t < 80) {
        int b = t / 10, j = t % 10;
        float acc = fc_b[j];
        for (int k = 0; k < 376; k++) acc += feat[b * 376 + k] * fc_w[k * 10 + j];
        logit[t] = acc;
    }
    __syncthreads();
    if (t < 8) {
        float m = -1e30f;
        for (int j = 0; j < 10; j++) m = fmaxf(m, logit[t * 10 + j]);
        float ssum = 0.f;
        for (int j = 0; j < 10; j++) ssum += expf(logit[t * 10 + j] - m);
        roff[t] = m + logf(ssum);
    }
    __syncthreads();
    if (t < 80) out[t] = logit[t] - roff[t / 10];
    if (t == 0) {
        float closs = 0.f;
        closs += sq[0] * (1.0f / 12582912.0f);
        closs += sq[1] * (1.0f / 78643200.0f);
        closs += sq[2] * (1.0f / 42205184.0f);
        closs += sq[3] * (1.0f / 18284544.0f);
        closs += sq[4] * (1.0f / 7028736.0f);
        out[80] = closs;
    }
}

// ---------------------------------------------------------------------------

extern "C" void kernel_launch(void* const* d_in, const int* in_sizes, int n_in,
                              void* d_out, int out_size, void* d_ws, size_t ws_size,
                              hipStream_t stream)
{
    static const int NSa[6] = {65536, 16384, 4096, 1024, 256, 64};
    static const int ESa[5] = {1048576, 262144, 65536, 16384, 4096};
    static const int COa[5] = {12, 20, 28, 36, 44};
    static const int CIa[5] = {1, 15, 23, 31, 39};

    const float* x0   = (const float*)d_in[0];
    const float* pos0 = (const float*)d_in[1];

    // ---- workspace layout (words), ~30 MB total ----
    int* wsw = (int*)d_ws;
    size_t off = 0;
    auto alw = [&](size_t n) -> size_t {
        size_t p = off; off += (n + 63) & ~(size_t)63; return p;
    };
    size_t degO[5], cdegO[5];
    for (int l = 1; l < 5; l++) degO[l]  = alw(NSa[l]);
    for (int l = 0; l < 5; l++) cdegO[l] = alw(NSa[l + 1]);
    size_t HO = alw(100);
    size_t zeroWords = off;                               // zero-init to here
    size_t rpO[5], crpO[5], eidO[5], cnidO[5];
    for (int l = 1; l < 5; l++) rpO[l]  = alw(NSa[l] + 1);
    for (int l = 0; l < 5; l++) crpO[l] = alw(NSa[l + 1] + 1);
    for (int l = 1; l < 5; l++) eidO[l] = alw(ESa[l]);
    for (int l = 0; l < 5; l++) cnidO[l] = alw(NSa[l]);
    size_t tsO  = alw(64);
    size_t toO  = alw(64);
    size_t MO   = alw((size_t)TILES0 * NB0);
    size_t M2O  = alw((size_t)TILES0 * NB0);
    size_t ctO  = alw(NB0);
    size_t bsO  = alw(NB0 + 1);
    size_t payO = alw((size_t)ESa[0] * 4);                // 16B records
    size_t yO   = alw((size_t)65536 * 12);
    size_t sqO  = alw(8);
    size_t xnO[5], pnO[5];
    for (int l = 0; l < 5; l++) xnO[l] = alw((size_t)NSa[l + 1] * (COa[l] + 3));
    for (int l = 0; l < 5; l++) pnO[l] = alw((size_t)NSa[l + 1] * 3);

    hipMemsetAsync(d_ws, 0, zeroWords * 4, stream);

    // ---- segs 1-9 descriptor (edge segs 1-4 + cluster segs 0-4) ----
    SegArgs sa{};
    int nseg = 0;
    for (int l = 1; l < 5; l++) {
        sa.idx[nseg] = (const int*)d_in[3 + 10 * l];
        sa.cnt[nseg] = wsw + degO[l];
        sa.rp [nseg] = wsw + rpO[l];
        sa.out[nseg] = wsw + eidO[l];
        sa.n  [nseg] = ESa[l];
        sa.nb [nseg] = NSa[l];
        nseg++;
    }
    for (int l = 0; l < 5; l++) {
        sa.idx[nseg] = (const int*)d_in[5 + 10 * l];
        sa.cnt[nseg] = wsw + cdegO[l];
        sa.rp [nseg] = wsw + crpO[l];
        sa.out[nseg] = wsw + cnidO[l];
        sa.n  [nseg] = NSa[l];
        sa.nb [nseg] = NSa[l + 1];
        nseg++;
    }
    ScanAux sx{};
    int tiles = 0, btiles = 0;
    for (int s = 0; s < nseg; s++) {
        int lg = 31 - __builtin_clz(sa.nb[s]);
        sa.shift[s] = lg - 3;
        sa.tstart[s] = tiles;
        tiles += (sa.n[s] + 255) / 256;
        sx.sstart[s] = btiles;
        btiles += (sa.nb[s] + 4095) / 4096;
    }
    for (int s = nseg; s <= 10; s++) {
        sa.tstart[s] = tiles;
        sx.sstart[s] = btiles;
        if (s < 10) {
            sa.idx[s] = sa.idx[nseg - 1]; sa.cnt[s] = sa.cnt[nseg - 1];
            sa.rp[s] = sa.rp[nseg - 1];   sa.out[s] = sa.out[nseg - 1];
            sa.n[s] = 0; sa.nb[s] = 8; sa.shift[s] = 0;
        }
    }
    sx.T = btiles;
    sx.tilesum = wsw + tsO;
    sx.tileoff = wsw + toO;

    float4* pay2 = (float4*)(wsw + payO);
    float*  Hp   = (float*)(wsw + HO);

    // ---- seg0 deterministic radix build + fused h/stats ----
    cnt0_k   <<<TILES0, 256, 0, stream>>>((const int*)d_in[3], wsw + MO);
    colscan_k<<<NB0, 256, 0, stream>>>(wsw + MO, wsw + M2O, wsw + ctO);
    bktscan_k<<<1, NB0, 0, stream>>>(wsw + ctO, wsw + bsO);
    part0_k  <<<TILES0, 256, 0, stream>>>(
        (const int*)d_in[2], (const int*)d_in[3], (const float*)d_in[4],
        x0, wsw + M2O, wsw + bsO, pay2,
        (const float*)d_in[6], (const float*)d_in[7], Hp);

    // ---- segs 1-9 atomic build ----
    hist_all_k   <<<tiles * NBUCK, 256, 0, stream>>>(sa);
    scanA_k      <<<btiles, 256, 0, stream>>>(sa, sx);
    scanB_k      <<<1, 64, 0, stream>>>(sa, sx);
    scanC_k      <<<btiles, 256, 0, stream>>>(sa, sx);
    scatter_all_k<<<tiles * NBUCK, 256, 0, stream>>>(sa);

    // ---- closs statistics: hstats for levels 1-4 only ----
    HArgs ha{};
    int bs = 0;
    ha.bstart[0] = 0;
    ha.eattr[0] = (const float*)d_in[4];
    ha.w1[0] = (const float*)d_in[6];
    ha.b1[0] = (const float*)d_in[7];
    ha.E[0] = 0;
    for (int l = 1; l < 5; l++) {
        ha.eattr[l] = (const float*)d_in[4 + 10 * l];
        ha.w1[l]    = (const float*)d_in[6 + 10 * l];
        ha.b1[l]    = (const float*)d_in[7 + 10 * l];
        ha.E[l]     = ESa[l];
        ha.bstart[l] = bs;
        bs += (ESa[l] + 256 * 32 - 1) / (256 * 32);
    }
    ha.bstart[5] = bs;
    ha.H = Hp;
    hstats_k<<<bs, 256, 0, stream>>>(ha);

    WArgs wa{};
    for (int l = 0; l < 5; l++) {
        wa.w2[l]   = (const float*)d_in[8 + 10 * l];
        wa.b2[l]   = (const float*)d_in[9 + 10 * l];
        wa.cico[l] = CIa[l] * COa[l];
        wa.E[l]    = ESa[l];
    }
    wa.H  = Hp;
    wa.sq = (float*)(wsw + sqO);
    wstats_k<<<5, 64, 0, stream>>>(wa);

    float* yb = (float*)(wsw + yO);

    // ---- level 0: fused in-LDS CSR + register accumulation conv ----
    conv0c_k<<<NB0, 256, 0, stream>>>(
        pay2, wsw + bsO,
        (const float*)d_in[8], (const float*)d_in[9],
        (const float*)d_in[10], (const float*)d_in[11], x0, yb);
    pool_k<12><<<(NSa[1] * 15 + 255) / 256, 256, 0, stream>>>(
        NSa[1], wsw + crpO[0], wsw + cnidO[0], yb, pos0,
        (float*)(wsw + xnO[0]), (float*)(wsw + pnO[0]));

    // ---- levels 1-4 ----
#define LVLC(l, CI_, CO_) do {                                                 \
    const float* xin   = (const float*)(wsw + xnO[(l) - 1]);                   \
    const float* posin = (const float*)(wsw + pnO[(l) - 1]);                   \
    int N = NSa[(l)], NN = NSa[(l) + 1];                                       \
    coop_conv_k<CI_, CO_><<<N, 256, 0, stream>>>(                              \
        wsw + rpO[(l)], wsw + eidO[(l)],                                       \
        (const int*)d_in[2 + 10 * (l)], (const float*)d_in[4 + 10 * (l)],      \
        (const float*)d_in[6 + 10 * (l)], (const float*)d_in[7 + 10 * (l)],    \
        (const float*)d_in[8 + 10 * (l)], (const float*)d_in[9 + 10 * (l)],    \
        (const float*)d_in[10 + 10 * (l)], (const float*)d_in[11 + 10 * (l)],  \
        xin, yb);                                                              \
    pool_k<CO_><<<(NN * ((CO_) + 3) + 255) / 256, 256, 0, stream>>>(           \
        NN, wsw + crpO[(l)], wsw + cnidO[(l)], yb, posin,                      \
        (float*)(wsw + xnO[(l)]), (float*)(wsw + pnO[(l)]));                   \
} while (0)

    LVLC(1, 15, 20);
    LVLC(2, 23, 28);
    LVLC(3, 31, 36);
    LVLC(4, 39, 44);
#undef LVLC

    fc_k<<<1, 128, 0, stream>>>((const float*)(wsw + xnO[4]),
                                (const float*)d_in[52], (const float*)d_in[53],
                                (const float*)(wsw + sqO), (float*)d_out);
}

// Round 14
// 431.079 us; speedup vs baseline: 1.1238x; 1.0691x over previous
//
#include <hip/hip_runtime.h>
#include <hip/hip_fp16.h>
#include <math.h>

// ---------------------------------------------------------------------------
// Net_37512244363273: 5-level edge-conditioned graph conv + voxel pooling + FC
// Round 14: all kernels are now < the 43 us harness re-poison; estimated real
// work ~140 us vs dur 461 us with 23 dispatches -> ~10 us/dispatch launch
// overhead dominates. Merged independent phases via block-range multiplexing:
//   K2 countA  = cnt0 | hist_all | hstats(L1-4)
//   K3 scanP1  = colscan | scanA
//   K4 scanP2  = bktscan | scanB
//   K5 scanP3  = scanC | part0          (part0 fills H0 here)
//   K6 scatC   = scatter_all | conv0c | wstats
// 23 -> 16 dispatches. All kernel bodies identical to round 13 (verified:
// 461 us, absmax 0.0078). Output: 80 log_softmax + closs = 81 floats.
// ---------------------------------------------------------------------------

#define NBUCK 8
#define TILES0 256                 // seg0 tiles (4096 edges each)
#define NB0    512                 // seg0 buckets (dst>>7, 128 nodes each)
#define IDXCAP 3072                // per-bucket index capacity (mean 2048)

struct SegArgs {
    const int* idx[10];
    int*       cnt[10];
    int*       rp [10];
    int*       out[10];
    int        n  [10];
    int        nb [10];
    int        shift[10];
    int        tstart[11];
};

struct ScanAux {
    int* tilesum;
    int* tileoff;
    int  sstart[11];
    int  T;
};

struct HArgs {
    const float* eattr[5];
    const float* w1[5];
    const float* b1[5];
    float*       H;
    int          E[5];
    int          bstart[6];
};

struct WArgs {
    const float* w2[5];
    const float* b2[5];
    const float* H;
    float*       sq;
    int          cico[5];
    int          E[5];
};

// ---------------------------------------------------------------------------
// K2: countA = cnt0 (256 blocks) | hist_all (histBlocks) | hstats (rest)
// ---------------------------------------------------------------------------
__global__ __launch_bounds__(256) void countA_k(
    SegArgs a, HArgs ha, const int* __restrict__ dst0, int* __restrict__ M,
    int histBlocks)
{
    __shared__ int sh[NB0];                        // cnt0 hist / hstats red
    int B = blockIdx.x;
    int t = threadIdx.x;

    if (B < TILES0) {                              // ---- cnt0 body ----
        for (int u = t; u < NB0; u += 256) sh[u] = 0;
        __syncthreads();
        int base = B * 4096 + t;
        #pragma unroll
        for (int it = 0; it < 16; it++)
            atomicAdd(&sh[dst0[base + it * 256] >> 7], 1);
        __syncthreads();
        for (int u = t; u < NB0; u += 256) M[(size_t)B * NB0 + u] = sh[u];
        return;
    }
    B -= TILES0;
    if (B < histBlocks) {                          // ---- hist_all body ----
        int bucket = B % NBUCK;
        int T = B / NBUCK;
        int s = 0;
        while (s < 9 && T >= a.tstart[s + 1]) s++;
        int i = (T - a.tstart[s]) * 256 + t;
        if (i >= a.n[s]) return;
        int d = a.idx[s][i];
        if ((d >> a.shift[s]) != bucket) return;
        atomicAdd(&a.cnt[s][d], 1);
        return;
    }
    // ---- hstats body (levels 1-4) ----
    int b = B - histBlocks;
    const int K = 32;
    int l = 0;
    while (l < 4 && b >= ha.bstart[l + 1]) l++;
    int bloc = b - ha.bstart[l];
    const float* ea = ha.eattr[l];
    float w1r[15], b1r[5];
    #pragma unroll
    for (int i = 0; i < 15; i++) w1r[i] = ha.w1[l][i];
    #pragma unroll
    for (int i = 0; i < 5; i++)  b1r[i] = ha.b1[l][i];
    float acc[20];
    #pragma unroll
    for (int i = 0; i < 20; i++) acc[i] = 0.f;
    int base = bloc * 256 * K + t;
    for (int it = 0; it < K; it++) {
        int e = base + it * 256;
        if (e < ha.E[l]) {
            float e0 = ea[e * 3], e1 = ea[e * 3 + 1], e2 = ea[e * 3 + 2];
            float h[5];
            #pragma unroll
            for (int k = 0; k < 5; k++)
                h[k] = tanhf(e0 * w1r[k] + e1 * w1r[5 + k] + e2 * w1r[10 + k] + b1r[k]);
            int p = 5;
            #pragma unroll
            for (int k = 0; k < 5; k++) {
                acc[k] += h[k];
                #pragma unroll
                for (int k2 = k; k2 < 5; k2++) acc[p++] += h[k] * h[k2];
            }
        }
    }
    float* red = (float*)sh;                       // [4][20]
    int wid = t >> 6, lane = t & 63;
    #pragma unroll
    for (int v = 0; v < 20; v++) {
        float s = acc[v];
        #pragma unroll
        for (int o = 32; o; o >>= 1) s += __shfl_down(s, o);
        if (lane == 0) red[wid * 20 + v] = s;
    }
    __syncthreads();
    if (t < 20)
        atomicAdd(&ha.H[l * 20 + t],
                  red[t] + red[20 + t] + red[40 + t] + red[60 + t]);
}

// ---------------------------------------------------------------------------
// K3: scanP1 = colscan (NB0 blocks) | scanA (rest)
// ---------------------------------------------------------------------------
__global__ __launch_bounds__(256) void scanP1_k(
    SegArgs a, ScanAux x, const int* __restrict__ M, int* __restrict__ M2,
    int* __restrict__ colTotal)
{
    __shared__ int sc[256];
    int B = blockIdx.x;
    int t = threadIdx.x;

    if (B < NB0) {                                 // ---- colscan body ----
        int v = M[(size_t)t * NB0 + B];
        sc[t] = v;
        __syncthreads();
        for (int d = 1; d < 256; d <<= 1) {
            int u = (t >= d) ? sc[t - d] : 0;
            __syncthreads();
            sc[t] += u;
            __syncthreads();
        }
        M2[(size_t)t * NB0 + B] = sc[t] - v;
        if (t == 255) colTotal[B] = sc[255];
        return;
    }
    // ---- scanA body ----
    int b = B - NB0;
    int s = 0;
    while (s < 9 && b >= x.sstart[s + 1]) s++;
    int tloc = b - x.sstart[s];
    int nb = a.nb[s];
    const int* cnt = a.cnt[s];
    int i0 = tloc * 4096 + t * 16;
    int sum = 0;
    #pragma unroll
    for (int k = 0; k < 16; k++) {
        int i = i0 + k;
        if (i < nb) sum += cnt[i];
    }
    #pragma unroll
    for (int o = 32; o; o >>= 1) sum += __shfl_down(sum, o);
    if ((t & 63) == 0) sc[t >> 6] = sum;
    __syncthreads();
    if (t == 0)
        x.tilesum[b] = sc[0] + sc[1] + sc[2] + sc[3];
}

// ---------------------------------------------------------------------------
// K4: scanP2 = bktscan (block 0, 512 thr) | scanB (block 1, lanes < 64)
// ---------------------------------------------------------------------------
__global__ __launch_bounds__(512) void scanP2_k(
    SegArgs a, ScanAux x, const int* __restrict__ colTotal,
    int* __restrict__ bucketStart)
{
    __shared__ int sc[NB0];
    int t = threadIdx.x;
    if (blockIdx.x == 0) {                         // ---- bktscan body ----
        int v = colTotal[t];
        sc[t] = v;
        __syncthreads();
        for (int d = 1; d < NB0; d <<= 1) {
            int u = (t >= d) ? sc[t - d] : 0;
            __syncthreads();
            sc[t] += u;
            __syncthreads();
        }
        bucketStart[t] = sc[t] - v;
        if (t == NB0 - 1) bucketStart[NB0] = sc[NB0 - 1];
        return;
    }
    // ---- scanB body (wave 0 only) ----
    if (t >= 64) return;
    int lane = t;
    int orig = (lane < x.T) ? x.tilesum[lane] : 0;
    int val = orig;
    #pragma unroll
    for (int d = 1; d < 64; d <<= 1) {
        int v = __shfl_up(val, d);
        if (lane >= d) val += v;
    }
    int excl = val - orig;
    int s = 0;
    while (s < 9 && lane >= x.sstart[s + 1]) s++;
    int segExcl = __shfl(excl, x.sstart[s]);
    if (lane < x.T) {
        x.tileoff[lane] = excl - segExcl;
        if (lane == x.sstart[s + 1] - 1)
            a.rp[s][a.nb[s]] = val - segExcl;
    }
}

// ---------------------------------------------------------------------------
// K5: scanP3 = scanC (sx.T blocks) | part0 (TILES0 blocks)
// ---------------------------------------------------------------------------
__global__ __launch_bounds__(256) void scanP3_k(
    SegArgs a, ScanAux x,
    const int* __restrict__ src, const int* __restrict__ dst,
    const float* __restrict__ ea, const float* __restrict__ x0,
    const int* __restrict__ M2, const int* __restrict__ bucketStart,
    float4* __restrict__ pay2,
    const float* __restrict__ w1, const float* __restrict__ b1,
    float* __restrict__ H0)
{
    __shared__ int   shi[NB0];
    __shared__ float shf[100];                     // w1s[15] b1s[5] red[80]
    int B = blockIdx.x;
    int t = threadIdx.x;

    if (B < x.T) {                                 // ---- scanC body ----
        int s = 0;
        while (s < 9 && B >= x.sstart[s + 1]) s++;
        int tloc = B - x.sstart[s];
        int nb = a.nb[s];
        const int* cnt = a.cnt[s];
        int* rp = a.rp[s];
        int i0 = tloc * 4096 + t * 16;
        int v[16];
        int sum = 0;
        #pragma unroll
        for (int k = 0; k < 16; k++) {
            int i = i0 + k;
            v[k] = (i < nb) ? cnt[i] : 0;
            sum += v[k];
        }
        int acc = sum;
        shi[t] = acc;
        __syncthreads();
        for (int d = 1; d < 256; d <<= 1) {
            int t2 = (t >= d) ? shi[t - d] : 0;
            __syncthreads();
            acc += t2;
            shi[t] = acc;
            __syncthreads();
        }
        int running = x.tileoff[B] + (acc - sum);
        #pragma unroll
        for (int k = 0; k < 16; k++) {
            int i = i0 + k;
            if (i < nb) rp[i] = running;
            running += v[k];
        }
        return;
    }
    // ---- part0 body ----
    int tile = B - x.T;
    for (int u = t; u < NB0; u += 256)
        shi[u] = bucketStart[u] + M2[(size_t)tile * NB0 + u];
    if (t < 15) shf[t] = w1[t];
    if (t >= 32 && t < 37) shf[15 + t - 32] = b1[t - 32];
    __syncthreads();

    float acc[20];
    #pragma unroll
    for (int i = 0; i < 20; i++) acc[i] = 0.f;

    int base = tile * 4096 + t;
    #pragma unroll 4
    for (int it = 0; it < 16; it++) {
        int i = base + it * 256;
        int d = dst[i];
        float e0 = ea[i * 3], e1 = ea[i * 3 + 1], e2 = ea[i * 3 + 2];
        float h[5];
        #pragma unroll
        for (int k = 0; k < 5; k++)
            h[k] = tanhf(e0 * shf[k] + e1 * shf[5 + k] + e2 * shf[10 + k] + shf[15 + k]);
        int p = 5;
        #pragma unroll
        for (int k = 0; k < 5; k++) {
            acc[k] += h[k];
            #pragma unroll
            for (int k2 = k; k2 < 5; k2++) acc[p++] += h[k] * h[k2];
        }
        float xv = x0[src[i]];
        union HU { __half2 h2; float f; } p01, p23;
        p01.h2 = __floats2half2_rn(h[0], h[1]);
        p23.h2 = __floats2half2_rn(h[2], h[3]);
        unsigned wbits = ((unsigned)d << 16) |
                         (unsigned)__half_as_ushort(__float2half_rn(h[4]));
        int ps = atomicAdd(&shi[d >> 7], 1);       // LDS
        pay2[ps] = make_float4(xv, p01.f, p23.f, __uint_as_float(wbits));
    }

    int wid = t >> 6, lane = t & 63;
    #pragma unroll
    for (int v = 0; v < 20; v++) {
        float s = acc[v];
        #pragma unroll
        for (int o = 32; o; o >>= 1) s += __shfl_down(s, o);
        if (lane == 0) shf[20 + wid * 20 + v] = s;
    }
    __syncthreads();
    if (t < 20)
        atomicAdd(&H0[t], shf[20 + t] + shf[40 + t] + shf[60 + t] + shf[80 + t]);
}

// ---------------------------------------------------------------------------
// K6: scatC = scatter_all (histBlocks) | conv0c (NB0) | wstats (5)
// ---------------------------------------------------------------------------
__global__ __launch_bounds__(256) void scatC_k(
    SegArgs a, WArgs wa, int histBlocks,
    const float4* __restrict__ pay2, const int* __restrict__ bucketStart,
    const float* __restrict__ w2, const float* __restrict__ b2,
    const float* __restrict__ root, const float* __restrict__ bias,
    const float* __restrict__ x, float* __restrict__ y)
{
    __shared__ float wsm[96];                      // w2s[60] b2s[12] roots[12] biass[12]
    __shared__ int hist[128], st[128], cur[128];
    __shared__ int idxL[IDXCAP];
    int B = blockIdx.x;
    int t = threadIdx.x;

    if (B < histBlocks) {                          // ---- scatter_all body ----
        int bucket = B % NBUCK;
        int T = B / NBUCK;
        int s = 0;
        while (s < 9 && T >= a.tstart[s + 1]) s++;
        int i = (T - a.tstart[s]) * 256 + t;
        if (i >= a.n[s]) return;
        int d = a.idx[s][i];
        if ((d >> a.shift[s]) != bucket) return;
        int p = atomicSub(&a.cnt[s][d], 1) - 1;
        a.out[s][a.rp[s][d] + p] = i;
        return;
    }
    B -= histBlocks;
    if (B < NB0) {                                 // ---- conv0c body ----
        if (t < 60) wsm[t] = w2[t];
        else if (t >= 64  && t < 76)  wsm[60 + t - 64]  = b2[t - 64];
        else if (t >= 128 && t < 140) wsm[72 + t - 128] = root[t - 128];
        else if (t >= 192 && t < 204) wsm[84 + t - 192] = bias[t - 192];
        if (t < 128) hist[t] = 0;
        __syncthreads();

        int lo = bucketStart[B], hi = bucketStart[B + 1];
        int bin0 = B << 7;
        const float* payw = (const float*)pay2;
        for (int j = lo + t; j < hi; j += 256) {
            int rel = (int)(__float_as_uint(payw[4 * j + 3]) >> 16) - bin0;
            atomicAdd(&hist[rel], 1);
        }
        __syncthreads();
        if (t < 128) st[t] = hist[t];
        __syncthreads();
        for (int d = 1; d < 128; d <<= 1) {
            int u = (t < 128 && t >= d) ? st[t - d] : 0;
            __syncthreads();
            if (t < 128) st[t] += u;
            __syncthreads();
        }
        if (t < 128) cur[t] = st[t] - hist[t];
        __syncthreads();
        for (int j = lo + t; j < hi; j += 256) {
            int rel = (int)(__float_as_uint(payw[4 * j + 3]) >> 16) - bin0;
            int p = atomicAdd(&cur[rel], 1);
            idxL[p] = j;
        }
        __syncthreads();

        if (t < 128) {
            int v = bin0 + t;
            int deg = hist[t];
            int s0 = st[t] - deg;
            float S0 = 0.f, S1 = 0.f, S2 = 0.f, S3 = 0.f, S4 = 0.f, S5 = 0.f;
            for (int jj = s0; jj < s0 + deg; jj++) {
                float4 R = pay2[idxL[jj]];
                union HU { float f; __half2 h2; } a01, a23;
                a01.f = R.y; a23.f = R.z;
                unsigned wbits = __float_as_uint(R.w);
                float xv = R.x;
                S0 += xv;
                S1 += __low2float(a01.h2)  * xv;
                S2 += __high2float(a01.h2) * xv;
                S3 += __low2float(a23.h2)  * xv;
                S4 += __high2float(a23.h2) * xv;
                S5 += __half2float(__ushort_as_half((unsigned short)(wbits & 0xffffu))) * xv;
            }
            float inv = 1.f / fmaxf((float)deg, 1.f);
            float xv = x[v];
            #pragma unroll
            for (int o = 0; o < 12; o++) {
                float msg = wsm[60 + o] * S0 + wsm[o] * S1 + wsm[12 + o] * S2 +
                            wsm[24 + o] * S3 + wsm[36 + o] * S4 + wsm[48 + o] * S5;
                y[v * 12 + o] = msg * inv + xv * wsm[72 + o] + wsm[84 + o];
            }
        }
        return;
    }
    // ---- wstats body (wave 0 only) ----
    if (t >= 64) return;
    int l = B - NB0;
    const float* w2l = wa.w2[l];
    const float* b2l = wa.b2[l];
    int cico = wa.cico[l];
    float d[21];
    #pragma unroll
    for (int i = 0; i < 21; i++) d[i] = 0.f;
    for (int u = t; u < cico; u += 64) {
        float b = b2l[u];
        float w[5];
        #pragma unroll
        for (int k = 0; k < 5; k++) w[k] = w2l[k * cico + u];
        int p = 0;
        #pragma unroll
        for (int k = 0; k < 5; k++) {
            #pragma unroll
            for (int k2 = k; k2 < 5; k2++) d[p++] += w[k] * w[k2];
        }
        #pragma unroll
        for (int k = 0; k < 5; k++) d[15 + k] += b * w[k];
        d[20] += b * b;
    }
    #pragma unroll
    for (int i = 0; i < 21; i++) {
        #pragma unroll
        for (int off = 32; off; off >>= 1) d[i] += __shfl_down(d[i], off);
    }
    if (t == 0) {
        const float* H1 = wa.H + l * 20;
        const float* H2 = H1 + 5;
        float sq = (float)wa.E[l] * d[20];
        #pragma unroll
        for (int k = 0; k < 5; k++) sq += 2.f * d[15 + k] * H1[k];
        int p = 0;
        #pragma unroll
        for (int k = 0; k < 5; k++) {
            #pragma unroll
            for (int k2 = k; k2 < 5; k2++) {
                sq += ((k == k2) ? 1.f : 2.f) * d[p] * H2[p];
                p++;
            }
        }
        wa.sq[l] = sq;
    }
}

// ---------------------------------------------------------------------------
// coop_conv_k (L1-L4), pool_k, fc_k: unchanged from round 13.
// ---------------------------------------------------------------------------
template<int CI, int CO>
__global__ __launch_bounds__(256) void coop_conv_k(
    const int* __restrict__ rp, const int* __restrict__ eid,
    const int* __restrict__ src, const float* __restrict__ eattr,
    const float* __restrict__ w1, const float* __restrict__ b1,
    const float* __restrict__ w2, const float* __restrict__ b2,
    const float* __restrict__ root, const float* __restrict__ bias,
    const float* __restrict__ x, float* __restrict__ y)
{
    constexpr int CH   = 48;
    constexpr int CICO = CI * CO;
    static_assert(6 * CI <= 256, "phase-A lanes");
    __shared__ float w1s[20];
    __shared__ int   eb[CH], svb[CH];
    __shared__ float hb[CH * 6];
    __shared__ float xs[CH * CI];
    __shared__ float S[6 * CI];

    int t = threadIdx.x;
    int v = blockIdx.x;
    if (t < 20) w1s[t] = (t < 15) ? w1[t] : b1[t - 15];
    int r0 = rp[v], r1 = rp[v + 1];
    int d  = r1 - r0;
    float acc = 0.f;

    for (int c0 = r0; c0 < r1; c0 += CH) {
        int cn = min(CH, r1 - c0);
        if (t < cn) {
            int e = eid[c0 + t];
            eb[t]  = e;
            svb[t] = src[e];
            hb[t * 6] = 1.f;
        }
        __syncthreads();
        if (t < cn * 5) {
            int j = t / 5, k = t % 5;
            int e = eb[j];
            float e0 = eattr[e * 3], e1 = eattr[e * 3 + 1], e2 = eattr[e * 3 + 2];
            hb[j * 6 + 1 + k] =
                tanhf(e0 * w1s[k] + e1 * w1s[5 + k] + e2 * w1s[10 + k] + w1s[15 + k]);
        }
        for (int u = t; u < cn * CI; u += 256)
            xs[u] = x[(size_t)svb[u / CI] * CI + (u % CI)];
        __syncthreads();
        if (t < 6 * CI) {
            int i = t / 6, k6 = t % 6;
            for (int j = 0; j < cn; j++)
                acc += hb[j * 6 + k6] * xs[j * CI + i];
        }
        __syncthreads();
    }

    if (t < 6 * CI) S[t] = acc;
    __syncthreads();

    if (t < CO) {
        float m = 0.f;
        for (int i = 0; i < CI; i++) {
            m += b2[i * CO + t] * S[i * 6];
            #pragma unroll
            for (int k = 0; k < 5; k++)
                m += w2[k * CICO + i * CO + t] * S[i * 6 + 1 + k];
        }
        m /= fmaxf((float)d, 1.f);
        for (int i = 0; i < CI; i++)
            m += x[(size_t)v * CI + i] * root[i * CO + t];
        y[(size_t)v * CO + t] = m + bias[t];
    }
}

template<int CO>
__global__ __launch_bounds__(256) void pool_k(
    int NN,
    const int* __restrict__ crp, const int* __restrict__ cnid,
    const float* __restrict__ y, const float* __restrict__ pos,
    float* __restrict__ xn, float* __restrict__ pn)
{
    int t = blockIdx.x * 256 + threadIdx.x;
    if (t >= NN * (CO + 3)) return;
    int c = t / (CO + 3), o = t % (CO + 3);
    int r0 = crp[c], r1 = crp[c + 1];
    int d = r1 - r0;
    if (o < CO) {
        float m = -INFINITY;
        for (int j = r0; j < r1; j++)
            m = fmaxf(m, y[(size_t)cnid[j] * CO + o]);
        if (d == 0 || !isfinite(m)) m = 0.f;
        xn[c * (CO + 3) + o] = m;
    } else {
        int k = o - CO;
        float sum = 0.f;
        for (int j = r0; j < r1; j++)
            sum += pos[cnid[j] * 3 + k];
        float pm = sum / fmaxf((float)d, 1.f);
        xn[c * (CO + 3) + CO + k] = pm;
        pn[c * 3 + k] = pm;
    }
}

__global__ __launch_bounds__(128) void fc_k(
    const float* __restrict__ x5,
    const float* __restrict__ fc_w, const float* __restrict__ fc_b,
    const float* __restrict__ sq, float* __restrict__ out)
{
    __shared__ float feat[8 * 376];
    __shared__ float logit[80];
    __shared__ float roff[8];
    for (int t = threadIdx.x; t < 8 * 376; t += 128) feat[t] = x5[t];
    __syncthreads();
    int t = threadIdx.x;
    if (t < 80) {
        int b = t / 10, j = t % 10;
        float acc = fc_b[j];
        for (int k = 0; k < 376; k++) acc += feat[b * 376 + k] * fc_w[k * 10 + j];
        logit[t] = acc;
    }
    __syncthreads();
    if (t < 8) {
        float m = -1e30f;
        for (int j = 0; j < 10; j++) m = fmaxf(m, logit[t * 10 + j]);
        float ssum = 0.f;
        for (int j = 0; j < 10; j++) ssum += expf(logit[t * 10 + j] - m);
        roff[t] = m + logf(ssum);
    }
    __syncthreads();
    if (t < 80) out[t] = logit[t] - roff[t / 10];
    if (t == 0) {
        float closs = 0.f;
        closs += sq[0] * (1.0f / 12582912.0f);
        closs += sq[1] * (1.0f / 78643200.0f);
        closs += sq[2] * (1.0f / 42205184.0f);
        closs += sq[3] * (1.0f / 18284544.0f);
        closs += sq[4] * (1.0f / 7028736.0f);
        out[80] = closs;
    }
}

// ---------------------------------------------------------------------------

extern "C" void kernel_launch(void* const* d_in, const int* in_sizes, int n_in,
                              void* d_out, int out_size, void* d_ws, size_t ws_size,
                              hipStream_t stream)
{
    static const int NSa[6] = {65536, 16384, 4096, 1024, 256, 64};
    static const int ESa[5] = {1048576, 262144, 65536, 16384, 4096};
    static const int COa[5] = {12, 20, 28, 36, 44};
    static const int CIa[5] = {1, 15, 23, 31, 39};

    const float* x0   = (const float*)d_in[0];
    const float* pos0 = (const float*)d_in[1];

    // ---- workspace layout (words), ~30 MB total ----
    int* wsw = (int*)d_ws;
    size_t off = 0;
    auto alw = [&](size_t n) -> size_t {
        size_t p = off; off += (n + 63) & ~(size_t)63; return p;
    };
    size_t degO[5], cdegO[5];
    for (int l = 1; l < 5; l++) degO[l]  = alw(NSa[l]);
    for (int l = 0; l < 5; l++) cdegO[l] = alw(NSa[l + 1]);
    size_t HO = alw(100);
    size_t zeroWords = off;                               // zero-init to here
    size_t rpO[5], crpO[5], eidO[5], cnidO[5];
    for (int l = 1; l < 5; l++) rpO[l]  = alw(NSa[l] + 1);
    for (int l = 0; l < 5; l++) crpO[l] = alw(NSa[l + 1] + 1);
    for (int l = 1; l < 5; l++) eidO[l] = alw(ESa[l]);
    for (int l = 0; l < 5; l++) cnidO[l] = alw(NSa[l]);
    size_t tsO  = alw(64);
    size_t toO  = alw(64);
    size_t MO   = alw((size_t)TILES0 * NB0);
    size_t M2O  = alw((size_t)TILES0 * NB0);
    size_t ctO  = alw(NB0);
    size_t bsO  = alw(NB0 + 1);
    size_t payO = alw((size_t)ESa[0] * 4);                // 16B records
    size_t yO   = alw((size_t)65536 * 12);
    size_t sqO  = alw(8);
    size_t xnO[5], pnO[5];
    for (int l = 0; l < 5; l++) xnO[l] = alw((size_t)NSa[l + 1] * (COa[l] + 3));
    for (int l = 0; l < 5; l++) pnO[l] = alw((size_t)NSa[l + 1] * 3);

    hipMemsetAsync(d_ws, 0, zeroWords * 4, stream);

    // ---- segs 1-9 descriptor (edge segs 1-4 + cluster segs 0-4) ----
    SegArgs sa{};
    int nseg = 0;
    for (int l = 1; l < 5; l++) {
        sa.idx[nseg] = (const int*)d_in[3 + 10 * l];
        sa.cnt[nseg] = wsw + degO[l];
        sa.rp [nseg] = wsw + rpO[l];
        sa.out[nseg] = wsw + eidO[l];
        sa.n  [nseg] = ESa[l];
        sa.nb [nseg] = NSa[l];
        nseg++;
    }
    for (int l = 0; l < 5; l++) {
        sa.idx[nseg] = (const int*)d_in[5 + 10 * l];
        sa.cnt[nseg] = wsw + cdegO[l];
        sa.rp [nseg] = wsw + crpO[l];
        sa.out[nseg] = wsw + cnidO[l];
        sa.n  [nseg] = NSa[l];
        sa.nb [nseg] = NSa[l + 1];
        nseg++;
    }
    ScanAux sx{};
    int tiles = 0, btiles = 0;
    for (int s = 0; s < nseg; s++) {
        int lg = 31 - __builtin_clz(sa.nb[s]);
        sa.shift[s] = lg - 3;
        sa.tstart[s] = tiles;
        tiles += (sa.n[s] + 255) / 256;
        sx.sstart[s] = btiles;
        btiles += (sa.nb[s] + 4095) / 4096;
    }
    for (int s = nseg; s <= 10; s++) {
        sa.tstart[s] = tiles;
        sx.sstart[s] = btiles;
        if (s < 10) {
            sa.idx[s] = sa.idx[nseg - 1]; sa.cnt[s] = sa.cnt[nseg - 1];
            sa.rp[s] = sa.rp[nseg - 1];   sa.out[s] = sa.out[nseg - 1];
            sa.n[s] = 0; sa.nb[s] = 8; sa.shift[s] = 0;
        }
    }
    sx.T = btiles;
    sx.tilesum = wsw + tsO;
    sx.tileoff = wsw + toO;
    int histBlocks = tiles * NBUCK;

    float4* pay2 = (float4*)(wsw + payO);
    float*  Hp   = (float*)(wsw + HO);

    // ---- hstats descriptor (levels 1-4) ----
    HArgs ha{};
    int bs = 0;
    ha.bstart[0] = 0;
    ha.eattr[0] = (const float*)d_in[4];
    ha.w1[0] = (const float*)d_in[6];
    ha.b1[0] = (const float*)d_in[7];
    ha.E[0] = 0;
    for (int l = 1; l < 5; l++) {
        ha.eattr[l] = (const float*)d_in[4 + 10 * l];
        ha.w1[l]    = (const float*)d_in[6 + 10 * l];
        ha.b1[l]    = (const float*)d_in[7 + 10 * l];
        ha.E[l]     = ESa[l];
        ha.bstart[l] = bs;
        bs += (ESa[l] + 256 * 32 - 1) / (256 * 32);
    }
    ha.bstart[5] = bs;
    ha.H = Hp;

    WArgs wa{};
    for (int l = 0; l < 5; l++) {
        wa.w2[l]   = (const float*)d_in[8 + 10 * l];
        wa.b2[l]   = (const float*)d_in[9 + 10 * l];
        wa.cico[l] = CIa[l] * COa[l];
        wa.E[l]    = ESa[l];
    }
    wa.H  = Hp;
    wa.sq = (float*)(wsw + sqO);

    // ---- K2: counts (cnt0 | hist_all | hstats) ----
    countA_k<<<TILES0 + histBlocks + bs, 256, 0, stream>>>(
        sa, ha, (const int*)d_in[3], wsw + MO, histBlocks);
    // ---- K3: colscan | scanA ----
    scanP1_k<<<NB0 + btiles, 256, 0, stream>>>(
        sa, sx, wsw + MO, wsw + M2O, wsw + ctO);
    // ---- K4: bktscan | scanB ----
    scanP2_k<<<2, 512, 0, stream>>>(sa, sx, wsw + ctO, wsw + bsO);
    // ---- K5: scanC | part0 ----
    scanP3_k<<<btiles + TILES0, 256, 0, stream>>>(
        sa, sx,
        (const int*)d_in[2], (const int*)d_in[3], (const float*)d_in[4],
        x0, wsw + M2O, wsw + bsO, pay2,
        (const float*)d_in[6], (const float*)d_in[7], Hp);

    float* yb = (float*)(wsw + yO);

    // ---- K6: scatter_all | conv0c | wstats ----
    scatC_k<<<histBlocks + NB0 + 5, 256, 0, stream>>>(
        sa, wa, histBlocks, pay2, wsw + bsO,
        (const float*)d_in[8], (const float*)d_in[9],
        (const float*)d_in[10], (const float*)d_in[11], x0, yb);

    pool_k<12><<<(NSa[1] * 15 + 255) / 256, 256, 0, stream>>>(
        NSa[1], wsw + crpO[0], wsw + cnidO[0], yb, pos0,
        (float*)(wsw + xnO[0]), (float*)(wsw + pnO[0]));

#define LVLC(l, CI_, CO_) do {                                                 \
    const float* xin   = (const float*)(wsw + xnO[(l) - 1]);                   \
    const float* posin = (const float*)(wsw + pnO[(l) - 1]);                   \
    int N = NSa[(l)], NN = NSa[(l) + 1];                                       \
    coop_conv_k<CI_, CO_><<<N, 256, 0, stream>>>(                              \
        wsw + rpO[(l)], wsw + eidO[(l)],                                       \
        (const int*)d_in[2 + 10 * (l)], (const float*)d_in[4 + 10 * (l)],      \
        (const float*)d_in[6 + 10 * (l)], (const float*)d_in[7 + 10 * (l)],    \
        (const float*)d_in[8 + 10 * (l)], (const float*)d_in[9 + 10 * (l)],    \
        (const float*)d_in[10 + 10 * (l)], (const float*)d_in[11 + 10 * (l)],  \
        xin, yb);                                                              \
    pool_k<CO_><<<(NN * ((CO_) + 3) + 255) / 256, 256, 0, stream>>>(           \
        NN, wsw + crpO[(l)], wsw + cnidO[(l)], yb, posin,                      \
        (float*)(wsw + xnO[(l)]), (float*)(wsw + pnO[(l)]));                   \
} while (0)

    LVLC(1, 15, 20);
    LVLC(2, 23, 28);
    LVLC(3, 31, 36);
    LVLC(4, 39, 44);
#undef LVLC

    fc_k<<<1, 128, 0, stream>>>((const float*)(wsw + xnO[4]),
                                (const float*)d_in[52], (const float*)d_in[53],
                                wa.sq, (float*)d_out);
}

// Round 15
// 417.957 us; speedup vs baseline: 1.1591x; 1.0314x over previous
//
#include <hip/hip_runtime.h>
#include <hip/hip_fp16.h>
#include <math.h>

// ---------------------------------------------------------------------------
// Net_37512244363273: 5-level edge-conditioned graph conv + voxel pooling + FC
// Round 15: countA's pole was the segs1-9 bucketed atomic histogram (13.6K
// latency-bubble blocks, 435K device atomics); seg1 = 60% of those elements.
// Seg1 now uses the verified seg0-style deterministic matrix-scan radix:
// key=(dst<<16)|src, 16B records (key,ea0,ea1,ea2), M1[64x512] -> colscan1/
// bktscan1 (K3/K4 ranges) -> part1 (K5 range) -> bucket1 (K6 range) emitting
// rp1 + dst-sorted records. L1 conv (conv1s_k) streams contiguous records
// (no eid/eattr gathers). hist/scatter cover only segs 2-9 (173K elements).
// Still 16 dispatches. Output: 80 log_softmax + closs = 81 floats.
// ---------------------------------------------------------------------------

#define NBUCK 8
#define TILES0 256                 // seg0 tiles (4096 edges each)
#define NB0    512                 // seg0 buckets (dst>>7, 128 nodes each)
#define IDXCAP 3072                // seg0 per-bucket index capacity
#define TILES1 64                  // seg1 tiles (4096 edges each)
#define NB1    512                 // seg1 buckets (dst>>5, 32 nodes each)

struct SegArgs {
    const int* idx[10];
    int*       cnt[10];
    int*       rp [10];
    int*       out[10];
    int        n  [10];
    int        nb [10];
    int        shift[10];
    int        tstart[11];
};

struct ScanAux {
    int* tilesum;
    int* tileoff;
    int  sstart[11];
    int  T;
};

struct HArgs {
    const float* eattr[5];
    const float* w1[5];
    const float* b1[5];
    float*       H;
    int          E[5];
    int          bstart[6];
};

struct WArgs {
    const float* w2[5];
    const float* b2[5];
    const float* H;
    float*       sq;
    int          cico[5];
    int          E[5];
};

// ---------------------------------------------------------------------------
// K2: countA = cnt0 (256) | cnt1 (64) | hist_all (histBlocks) | hstats (rest)
// ---------------------------------------------------------------------------
__global__ __launch_bounds__(256) void countA_k(
    SegArgs a, HArgs ha, const int* __restrict__ dst0,
    const int* __restrict__ dst1, int* __restrict__ M, int* __restrict__ M1,
    int histBlocks)
{
    __shared__ int sh[NB0];
    int B = blockIdx.x;
    int t = threadIdx.x;

    if (B < TILES0) {                              // ---- cnt0 ----
        for (int u = t; u < NB0; u += 256) sh[u] = 0;
        __syncthreads();
        int base = B * 4096 + t;
        #pragma unroll
        for (int it = 0; it < 16; it++)
            atomicAdd(&sh[dst0[base + it * 256] >> 7], 1);
        __syncthreads();
        for (int u = t; u < NB0; u += 256) M[(size_t)B * NB0 + u] = sh[u];
        return;
    }
    B -= TILES0;
    if (B < TILES1) {                              // ---- cnt1 ----
        for (int u = t; u < NB1; u += 256) sh[u] = 0;
        __syncthreads();
        int base = B * 4096 + t;
        #pragma unroll
        for (int it = 0; it < 16; it++)
            atomicAdd(&sh[dst1[base + it * 256] >> 5], 1);
        __syncthreads();
        for (int u = t; u < NB1; u += 256) M1[(size_t)B * NB1 + u] = sh[u];
        return;
    }
    B -= TILES1;
    if (B < histBlocks) {                          // ---- hist_all (segs 2-9) ----
        int bucket = B % NBUCK;
        int T = B / NBUCK;
        int s = 0;
        while (s < 9 && T >= a.tstart[s + 1]) s++;
        int i = (T - a.tstart[s]) * 256 + t;
        if (i >= a.n[s]) return;
        int d = a.idx[s][i];
        if ((d >> a.shift[s]) != bucket) return;
        atomicAdd(&a.cnt[s][d], 1);
        return;
    }
    // ---- hstats (levels 1-4) ----
    int b = B - histBlocks;
    const int K = 32;
    int l = 0;
    while (l < 4 && b >= ha.bstart[l + 1]) l++;
    int bloc = b - ha.bstart[l];
    const float* ea = ha.eattr[l];
    float w1r[15], b1r[5];
    #pragma unroll
    for (int i = 0; i < 15; i++) w1r[i] = ha.w1[l][i];
    #pragma unroll
    for (int i = 0; i < 5; i++)  b1r[i] = ha.b1[l][i];
    float acc[20];
    #pragma unroll
    for (int i = 0; i < 20; i++) acc[i] = 0.f;
    int base = bloc * 256 * K + t;
    for (int it = 0; it < K; it++) {
        int e = base + it * 256;
        if (e < ha.E[l]) {
            float e0 = ea[e * 3], e1 = ea[e * 3 + 1], e2 = ea[e * 3 + 2];
            float h[5];
            #pragma unroll
            for (int k = 0; k < 5; k++)
                h[k] = tanhf(e0 * w1r[k] + e1 * w1r[5 + k] + e2 * w1r[10 + k] + b1r[k]);
            int p = 5;
            #pragma unroll
            for (int k = 0; k < 5; k++) {
                acc[k] += h[k];
                #pragma unroll
                for (int k2 = k; k2 < 5; k2++) acc[p++] += h[k] * h[k2];
            }
        }
    }
    float* red = (float*)sh;
    int wid = t >> 6, lane = t & 63;
    #pragma unroll
    for (int v = 0; v < 20; v++) {
        float s = acc[v];
        #pragma unroll
        for (int o = 32; o; o >>= 1) s += __shfl_down(s, o);
        if (lane == 0) red[wid * 20 + v] = s;
    }
    __syncthreads();
    if (t < 20)
        atomicAdd(&ha.H[l * 20 + t],
                  red[t] + red[20 + t] + red[40 + t] + red[60 + t]);
}

// ---------------------------------------------------------------------------
// K3: scanP1 = colscan0 (NB0) | colscan1 (NB1) | scanA (rest)
// ---------------------------------------------------------------------------
__global__ __launch_bounds__(256) void scanP1_k(
    SegArgs a, ScanAux x, const int* __restrict__ M, int* __restrict__ M2,
    int* __restrict__ colTotal, const int* __restrict__ M1,
    int* __restrict__ M21, int* __restrict__ ct1)
{
    __shared__ int sc[256];
    int B = blockIdx.x;
    int t = threadIdx.x;

    if (B < NB0) {                                 // ---- colscan0 ----
        int v = M[(size_t)t * NB0 + B];
        sc[t] = v;
        __syncthreads();
        for (int d = 1; d < 256; d <<= 1) {
            int u = (t >= d) ? sc[t - d] : 0;
            __syncthreads();
            sc[t] += u;
            __syncthreads();
        }
        M2[(size_t)t * NB0 + B] = sc[t] - v;
        if (t == 255) colTotal[B] = sc[255];
        return;
    }
    B -= NB0;
    if (B < NB1) {                                 // ---- colscan1 (64 tiles, wave 0) ----
        if (t >= 64) return;
        int v = M1[(size_t)t * NB1 + B];
        int val = v;
        #pragma unroll
        for (int d = 1; d < 64; d <<= 1) {
            int u = __shfl_up(val, d);
            if (t >= d) val += u;
        }
        M21[(size_t)t * NB1 + B] = val - v;
        if (t == 63) ct1[B] = val;
        return;
    }
    // ---- scanA (segs 2-9) ----
    int b = B - NB1;
    int s = 0;
    while (s < 9 && b >= x.sstart[s + 1]) s++;
    int tloc = b - x.sstart[s];
    int nb = a.nb[s];
    const int* cnt = a.cnt[s];
    int i0 = tloc * 4096 + t * 16;
    int sum = 0;
    #pragma unroll
    for (int k = 0; k < 16; k++) {
        int i = i0 + k;
        if (i < nb) sum += cnt[i];
    }
    #pragma unroll
    for (int o = 32; o; o >>= 1) sum += __shfl_down(sum, o);
    if ((t & 63) == 0) sc[t >> 6] = sum;
    __syncthreads();
    if (t == 0)
        x.tilesum[b] = sc[0] + sc[1] + sc[2] + sc[3];
}

// ---------------------------------------------------------------------------
// K4: scanP2 = bktscan0 (blk 0) | scanB (blk 1) | bktscan1 (blk 2)
// ---------------------------------------------------------------------------
__global__ __launch_bounds__(512) void scanP2_k(
    SegArgs a, ScanAux x, const int* __restrict__ colTotal,
    int* __restrict__ bucketStart, const int* __restrict__ ct1,
    int* __restrict__ bs1)
{
    __shared__ int sc[NB0];
    int t = threadIdx.x;
    if (blockIdx.x == 0) {                         // ---- bktscan0 ----
        int v = colTotal[t];
        sc[t] = v;
        __syncthreads();
        for (int d = 1; d < NB0; d <<= 1) {
            int u = (t >= d) ? sc[t - d] : 0;
            __syncthreads();
            sc[t] += u;
            __syncthreads();
        }
        bucketStart[t] = sc[t] - v;
        if (t == NB0 - 1) bucketStart[NB0] = sc[NB0 - 1];
        return;
    }
    if (blockIdx.x == 2) {                         // ---- bktscan1 ----
        int v = ct1[t];
        sc[t] = v;
        __syncthreads();
        for (int d = 1; d < NB1; d <<= 1) {
            int u = (t >= d) ? sc[t - d] : 0;
            __syncthreads();
            sc[t] += u;
            __syncthreads();
        }
        bs1[t] = sc[t] - v;
        if (t == NB1 - 1) bs1[NB1] = sc[NB1 - 1];
        return;
    }
    // ---- scanB (wave 0) ----
    if (t >= 64) return;
    int lane = t;
    int orig = (lane < x.T) ? x.tilesum[lane] : 0;
    int val = orig;
    #pragma unroll
    for (int d = 1; d < 64; d <<= 1) {
        int v = __shfl_up(val, d);
        if (lane >= d) val += v;
    }
    int excl = val - orig;
    int s = 0;
    while (s < 9 && lane >= x.sstart[s + 1]) s++;
    int segExcl = __shfl(excl, x.sstart[s]);
    if (lane < x.T) {
        x.tileoff[lane] = excl - segExcl;
        if (lane == x.sstart[s + 1] - 1)
            a.rp[s][a.nb[s]] = val - segExcl;
    }
}

// ---------------------------------------------------------------------------
// K5: scanP3 = scanC (sx.T) | part0 (TILES0) | part1 (TILES1)
// ---------------------------------------------------------------------------
__global__ __launch_bounds__(256) void scanP3_k(
    SegArgs a, ScanAux x,
    const int* __restrict__ src, const int* __restrict__ dst,
    const float* __restrict__ ea, const float* __restrict__ x0,
    const int* __restrict__ M2, const int* __restrict__ bucketStart,
    float4* __restrict__ pay2,
    const float* __restrict__ w1, const float* __restrict__ b1,
    float* __restrict__ H0,
    const int* __restrict__ src1, const int* __restrict__ dst1,
    const float* __restrict__ ea1, const int* __restrict__ M21,
    const int* __restrict__ bs1, float4* __restrict__ pay1)
{
    __shared__ int   shi[NB0];
    __shared__ float shf[100];
    int B = blockIdx.x;
    int t = threadIdx.x;

    if (B < x.T) {                                 // ---- scanC (segs 2-9) ----
        int s = 0;
        while (s < 9 && B >= x.sstart[s + 1]) s++;
        int tloc = B - x.sstart[s];
        int nb = a.nb[s];
        const int* cnt = a.cnt[s];
        int* rp = a.rp[s];
        int i0 = tloc * 4096 + t * 16;
        int v[16];
        int sum = 0;
        #pragma unroll
        for (int k = 0; k < 16; k++) {
            int i = i0 + k;
            v[k] = (i < nb) ? cnt[i] : 0;
            sum += v[k];
        }
        int acc = sum;
        shi[t] = acc;
        __syncthreads();
        for (int d = 1; d < 256; d <<= 1) {
            int t2 = (t >= d) ? shi[t - d] : 0;
            __syncthreads();
            acc += t2;
            shi[t] = acc;
            __syncthreads();
        }
        int running = x.tileoff[B] + (acc - sum);
        #pragma unroll
        for (int k = 0; k < 16; k++) {
            int i = i0 + k;
            if (i < nb) rp[i] = running;
            running += v[k];
        }
        return;
    }
    B -= x.T;
    if (B < TILES0) {                              // ---- part0 ----
        int tile = B;
        for (int u = t; u < NB0; u += 256)
            shi[u] = bucketStart[u] + M2[(size_t)tile * NB0 + u];
        if (t < 15) shf[t] = w1[t];
        if (t >= 32 && t < 37) shf[15 + t - 32] = b1[t - 32];
        __syncthreads();

        float acc[20];
        #pragma unroll
        for (int i = 0; i < 20; i++) acc[i] = 0.f;

        int base = tile * 4096 + t;
        #pragma unroll 4
        for (int it = 0; it < 16; it++) {
            int i = base + it * 256;
            int d = dst[i];
            float e0 = ea[i * 3], e1 = ea[i * 3 + 1], e2 = ea[i * 3 + 2];
            float h[5];
            #pragma unroll
            for (int k = 0; k < 5; k++)
                h[k] = tanhf(e0 * shf[k] + e1 * shf[5 + k] + e2 * shf[10 + k] + shf[15 + k]);
            int p = 5;
            #pragma unroll
            for (int k = 0; k < 5; k++) {
                acc[k] += h[k];
                #pragma unroll
                for (int k2 = k; k2 < 5; k2++) acc[p++] += h[k] * h[k2];
            }
            float xv = x0[src[i]];
            union HU { __half2 h2; float f; } p01, p23;
            p01.h2 = __floats2half2_rn(h[0], h[1]);
            p23.h2 = __floats2half2_rn(h[2], h[3]);
            unsigned wbits = ((unsigned)d << 16) |
                             (unsigned)__half_as_ushort(__float2half_rn(h[4]));
            int ps = atomicAdd(&shi[d >> 7], 1);
            pay2[ps] = make_float4(xv, p01.f, p23.f, __uint_as_float(wbits));
        }

        int wid = t >> 6, lane = t & 63;
        #pragma unroll
        for (int v = 0; v < 20; v++) {
            float s = acc[v];
            #pragma unroll
            for (int o = 32; o; o >>= 1) s += __shfl_down(s, o);
            if (lane == 0) shf[20 + wid * 20 + v] = s;
        }
        __syncthreads();
        if (t < 20)
            atomicAdd(&H0[t], shf[20 + t] + shf[40 + t] + shf[60 + t] + shf[80 + t]);
        return;
    }
    // ---- part1: record = (key=(dst<<16)|src, ea0, ea1, ea2) ----
    int tile = B - TILES0;
    for (int u = t; u < NB1; u += 256)
        shi[u] = bs1[u] + M21[(size_t)tile * NB1 + u];
    __syncthreads();
    int base = tile * 4096 + t;
    #pragma unroll 4
    for (int it = 0; it < 16; it++) {
        int i = base + it * 256;
        int d = dst1[i];
        int key = (d << 16) | src1[i];
        float e0 = ea1[i * 3], e1 = ea1[i * 3 + 1], e2 = ea1[i * 3 + 2];
        int ps = atomicAdd(&shi[d >> 5], 1);
        pay1[ps] = make_float4(__int_as_float(key), e0, e1, e2);
    }
}

// ---------------------------------------------------------------------------
// K6: scatC = scatter_all (histBlocks) | conv0c (NB0) | wstats (5) |
//             bucket1 (NB1)
// ---------------------------------------------------------------------------
__global__ __launch_bounds__(256) void scatC_k(
    SegArgs a, WArgs wa, int histBlocks,
    const float4* __restrict__ pay2, const int* __restrict__ bucketStart,
    const float* __restrict__ w2, const float* __restrict__ b2,
    const float* __restrict__ root, const float* __restrict__ bias,
    const float* __restrict__ x, float* __restrict__ y,
    const float4* __restrict__ pay1, const int* __restrict__ bs1,
    int* __restrict__ rp1, float4* __restrict__ rec1)
{
    __shared__ float wsm[96];
    __shared__ int hist[128], st[128], cur[128];
    __shared__ int idxL[IDXCAP];
    int B = blockIdx.x;
    int t = threadIdx.x;

    if (B < histBlocks) {                          // ---- scatter_all (segs 2-9) ----
        int bucket = B % NBUCK;
        int T = B / NBUCK;
        int s = 0;
        while (s < 9 && T >= a.tstart[s + 1]) s++;
        int i = (T - a.tstart[s]) * 256 + t;
        if (i >= a.n[s]) return;
        int d = a.idx[s][i];
        if ((d >> a.shift[s]) != bucket) return;
        int p = atomicSub(&a.cnt[s][d], 1) - 1;
        a.out[s][a.rp[s][d] + p] = i;
        return;
    }
    B -= histBlocks;
    if (B < NB0) {                                 // ---- conv0c ----
        if (t < 60) wsm[t] = w2[t];
        else if (t >= 64  && t < 76)  wsm[60 + t - 64]  = b2[t - 64];
        else if (t >= 128 && t < 140) wsm[72 + t - 128] = root[t - 128];
        else if (t >= 192 && t < 204) wsm[84 + t - 192] = bias[t - 192];
        if (t < 128) hist[t] = 0;
        __syncthreads();

        int lo = bucketStart[B], hi = bucketStart[B + 1];
        int bin0 = B << 7;
        const float* payw = (const float*)pay2;
        for (int j = lo + t; j < hi; j += 256) {
            int rel = (int)(__float_as_uint(payw[4 * j + 3]) >> 16) - bin0;
            atomicAdd(&hist[rel], 1);
        }
        __syncthreads();
        if (t < 128) st[t] = hist[t];
        __syncthreads();
        for (int d = 1; d < 128; d <<= 1) {
            int u = (t < 128 && t >= d) ? st[t - d] : 0;
            __syncthreads();
            if (t < 128) st[t] += u;
            __syncthreads();
        }
        if (t < 128) cur[t] = st[t] - hist[t];
        __syncthreads();
        for (int j = lo + t; j < hi; j += 256) {
            int rel = (int)(__float_as_uint(payw[4 * j + 3]) >> 16) - bin0;
            int p = atomicAdd(&cur[rel], 1);
            idxL[p] = j;
        }
        __syncthreads();

        if (t < 128) {
            int v = bin0 + t;
            int deg = hist[t];
            int s0 = st[t] - deg;
            float S0 = 0.f, S1 = 0.f, S2 = 0.f, S3 = 0.f, S4 = 0.f, S5 = 0.f;
            for (int jj = s0; jj < s0 + deg; jj++) {
                float4 R = pay2[idxL[jj]];
                union HU { float f; __half2 h2; } a01, a23;
                a01.f = R.y; a23.f = R.z;
                unsigned wbits = __float_as_uint(R.w);
                float xv = R.x;
                S0 += xv;
                S1 += __low2float(a01.h2)  * xv;
                S2 += __high2float(a01.h2) * xv;
                S3 += __low2float(a23.h2)  * xv;
                S4 += __high2float(a23.h2) * xv;
                S5 += __half2float(__ushort_as_half((unsigned short)(wbits & 0xffffu))) * xv;
            }
            float inv = 1.f / fmaxf((float)deg, 1.f);
            float xv = x[v];
            #pragma unroll
            for (int o = 0; o < 12; o++) {
                float msg = wsm[60 + o] * S0 + wsm[o] * S1 + wsm[12 + o] * S2 +
                            wsm[24 + o] * S3 + wsm[36 + o] * S4 + wsm[48 + o] * S5;
                y[v * 12 + o] = msg * inv + xv * wsm[72 + o] + wsm[84 + o];
            }
        }
        return;
    }
    B -= NB0;
    if (B < 5) {                                   // ---- wstats (wave 0) ----
        if (t >= 64) return;
        int l = B;
        const float* w2l = wa.w2[l];
        const float* b2l = wa.b2[l];
        int cico = wa.cico[l];
        float d[21];
        #pragma unroll
        for (int i = 0; i < 21; i++) d[i] = 0.f;
        for (int u = t; u < cico; u += 64) {
            float b = b2l[u];
            float w[5];
            #pragma unroll
            for (int k = 0; k < 5; k++) w[k] = w2l[k * cico + u];
            int p = 0;
            #pragma unroll
            for (int k = 0; k < 5; k++) {
                #pragma unroll
                for (int k2 = k; k2 < 5; k2++) d[p++] += w[k] * w[k2];
            }
            #pragma unroll
            for (int k = 0; k < 5; k++) d[15 + k] += b * w[k];
            d[20] += b * b;
        }
        #pragma unroll
        for (int i = 0; i < 21; i++) {
            #pragma unroll
            for (int off = 32; off; off >>= 1) d[i] += __shfl_down(d[i], off);
        }
        if (t == 0) {
            const float* H1 = wa.H + l * 20;
            const float* H2 = H1 + 5;
            float sq = (float)wa.E[l] * d[20];
            #pragma unroll
            for (int k = 0; k < 5; k++) sq += 2.f * d[15 + k] * H1[k];
            int p = 0;
            #pragma unroll
            for (int k = 0; k < 5; k++) {
                #pragma unroll
                for (int k2 = k; k2 < 5; k2++) {
                    sq += ((k == k2) ? 1.f : 2.f) * d[p] * H2[p];
                    p++;
                }
            }
            wa.sq[l] = sq;
        }
        return;
    }
    // ---- bucket1: sort bucket's records by dst, emit rp1 + rec1 ----
    int b = B - 5;
    int lo = bs1[b], hi = bs1[b + 1];
    int bin0 = b << 5;
    if (t < 32) hist[t] = 0;
    __syncthreads();
    const float* payw = (const float*)pay1;
    for (int j = lo + t; j < hi; j += 256) {
        int rel = (int)(__float_as_uint(payw[4 * j]) >> 16) - bin0;
        atomicAdd(&hist[rel], 1);
    }
    __syncthreads();
    if (t < 32) {                                  // wave-level exclusive scan
        int v = hist[t];
        int val = v;
        #pragma unroll
        for (int d = 1; d < 32; d <<= 1) {
            int u = __shfl_up(val, d);
            if (t >= d) val += u;
        }
        st[t] = val - v;                           // exclusive
        cur[t] = lo + val - v;
        rp1[bin0 + t] = lo + val - v;
        if (b == NB1 - 1 && t == 31) rp1[NB1 * 32] = hi;
    }
    __syncthreads();
    for (int j = lo + t; j < hi; j += 256) {
        float4 R = pay1[j];
        int rel = (int)(__float_as_uint(R.x) >> 16) - bin0;
        int p = atomicAdd(&cur[rel], 1);
        rec1[p] = R;
    }
}

// ---------------------------------------------------------------------------
// conv1s_k (L1): block per node, streams contiguous dst-sorted records.
// Record = (key=(dst<<16)|src, ea0, ea1, ea2). Factored conv as coop_conv.
// ---------------------------------------------------------------------------
__global__ __launch_bounds__(256) void conv1s_k(
    const int* __restrict__ rp, const float4* __restrict__ rec,
    const float* __restrict__ w1, const float* __restrict__ b1,
    const float* __restrict__ w2, const float* __restrict__ b2,
    const float* __restrict__ root, const float* __restrict__ bias,
    const float* __restrict__ x, float* __restrict__ y)
{
    constexpr int CI = 15, CO = 20, CH = 48, CICO = CI * CO;
    __shared__ float w1s[20];
    __shared__ float4 recb[CH];
    __shared__ int   svb[CH];
    __shared__ float hb[CH * 6];
    __shared__ float xs[CH * CI];
    __shared__ float S[6 * CI];

    int t = threadIdx.x;
    int v = blockIdx.x;
    if (t < 20) w1s[t] = (t < 15) ? w1[t] : b1[t - 15];
    int r0 = rp[v], r1 = rp[v + 1];
    int d  = r1 - r0;
    float acc = 0.f;

    for (int c0 = r0; c0 < r1; c0 += CH) {
        int cn = min(CH, r1 - c0);
        if (t < cn) {
            float4 R = rec[c0 + t];
            recb[t] = R;
            svb[t]  = (int)(__float_as_uint(R.x) & 0xffffu);
            hb[t * 6] = 1.f;
        }
        __syncthreads();
        if (t < cn * 5) {
            int j = t / 5, k = t % 5;
            float e0 = recb[j].y, e1 = recb[j].z, e2 = recb[j].w;
            hb[j * 6 + 1 + k] =
                tanhf(e0 * w1s[k] + e1 * w1s[5 + k] + e2 * w1s[10 + k] + w1s[15 + k]);
        }
        for (int u = t; u < cn * CI; u += 256)
            xs[u] = x[(size_t)svb[u / CI] * CI + (u % CI)];
        __syncthreads();
        if (t < 6 * CI) {
            int i = t / 6, k6 = t % 6;
            for (int j = 0; j < cn; j++)
                acc += hb[j * 6 + k6] * xs[j * CI + i];
        }
        __syncthreads();
    }

    if (t < 6 * CI) S[t] = acc;
    __syncthreads();

    if (t < CO) {
        float m = 0.f;
        for (int i = 0; i < CI; i++) {
            m += b2[i * CO + t] * S[i * 6];
            #pragma unroll
            for (int k = 0; k < 5; k++)
                m += w2[k * CICO + i * CO + t] * S[i * 6 + 1 + k];
        }
        m /= fmaxf((float)d, 1.f);
        for (int i = 0; i < CI; i++)
            m += x[(size_t)v * CI + i] * root[i * CO + t];
        y[(size_t)v * CO + t] = m + bias[t];
    }
}

// ---------------------------------------------------------------------------
// coop_conv_k (L2-L4), pool_k, fc_k: unchanged.
// ---------------------------------------------------------------------------
template<int CI, int CO>
__global__ __launch_bounds__(256) void coop_conv_k(
    const int* __restrict__ rp, const int* __restrict__ eid,
    const int* __restrict__ src, const float* __restrict__ eattr,
    const float* __restrict__ w1, const float* __restrict__ b1,
    const float* __restrict__ w2, const float* __restrict__ b2,
    const float* __restrict__ root, const float* __restrict__ bias,
    const float* __restrict__ x, float* __restrict__ y)
{
    constexpr int CH   = 48;
    constexpr int CICO = CI * CO;
    __shared__ float w1s[20];
    __shared__ int   eb[CH], svb[CH];
    __shared__ float hb[CH * 6];
    __shared__ float xs[CH * CI];
    __shared__ float S[6 * CI];

    int t = threadIdx.x;
    int v = blockIdx.x;
    if (t < 20) w1s[t] = (t < 15) ? w1[t] : b1[t - 15];
    int r0 = rp[v], r1 = rp[v + 1];
    int d  = r1 - r0;
    float acc = 0.f;

    for (int c0 = r0; c0 < r1; c0 += CH) {
        int cn = min(CH, r1 - c0);
        if (t < cn) {
            int e = eid[c0 + t];
            eb[t]  = e;
            svb[t] = src[e];
            hb[t * 6] = 1.f;
        }
        __syncthreads();
        if (t < cn * 5) {
            int j = t / 5, k = t % 5;
            int e = eb[j];
            float e0 = eattr[e * 3], e1 = eattr[e * 3 + 1], e2 = eattr[e * 3 + 2];
            hb[j * 6 + 1 + k] =
                tanhf(e0 * w1s[k] + e1 * w1s[5 + k] + e2 * w1s[10 + k] + w1s[15 + k]);
        }
        for (int u = t; u < cn * CI; u += 256)
            xs[u] = x[(size_t)svb[u / CI] * CI + (u % CI)];
        __syncthreads();
        if (t < 6 * CI) {
            int i = t / 6, k6 = t % 6;
            for (int j = 0; j < cn; j++)
                acc += hb[j * 6 + k6] * xs[j * CI + i];
        }
        __syncthreads();
    }

    if (t < 6 * CI) S[t] = acc;
    __syncthreads();

    if (t < CO) {
        float m = 0.f;
        for (int i = 0; i < CI; i++) {
            m += b2[i * CO + t] * S[i * 6];
            #pragma unroll
            for (int k = 0; k < 5; k++)
                m += w2[k * CICO + i * CO + t] * S[i * 6 + 1 + k];
        }
        m /= fmaxf((float)d, 1.f);
        for (int i = 0; i < CI; i++)
            m += x[(size_t)v * CI + i] * root[i * CO + t];
        y[(size_t)v * CO + t] = m + bias[t];
    }
}

template<int CO>
__global__ __launch_bounds__(256) void pool_k(
    int NN,
    const int* __restrict__ crp, const int* __restrict__ cnid,
    const float* __restrict__ y, const float* __restrict__ pos,
    float* __restrict__ xn, float* __restrict__ pn)
{
    int t = blockIdx.x * 256 + threadIdx.x;
    if (t >= NN * (CO + 3)) return;
    int c = t / (CO + 3), o = t % (CO + 3);
    int r0 = crp[c], r1 = crp[c + 1];
    int d = r1 - r0;
    if (o < CO) {
        float m = -INFINITY;
        for (int j = r0; j < r1; j++)
            m = fmaxf(m, y[(size_t)cnid[j] * CO + o]);
        if (d == 0 || !isfinite(m)) m = 0.f;
        xn[c * (CO + 3) + o] = m;
    } else {
        int k = o - CO;
        float sum = 0.f;
        for (int j = r0; j < r1; j++)
            sum += pos[cnid[j] * 3 + k];
        float pm = sum / fmaxf((float)d, 1.f);
        xn[c * (CO + 3) + CO + k] = pm;
        pn[c * 3 + k] = pm;
    }
}

__global__ __launch_bounds__(128) void fc_k(
    const float* __restrict__ x5,
    const float* __restrict__ fc_w, const float* __restrict__ fc_b,
    const float* __restrict__ sq, float* __restrict__ out)
{
    __shared__ float feat[8 * 376];
    __shared__ float logit[80];
    __shared__ float roff[8];
    for (int t = threadIdx.x; t < 8 * 376; t += 128) feat[t] = x5[t];
    __syncthreads();
    int t = threadIdx.x;
    if (t < 80) {
        int b = t / 10, j = t % 10;
        float acc = fc_b[j];
        for (int k = 0; k < 376; k++) acc += feat[b * 376 + k] * fc_w[k * 10 + j];
        logit[t] = acc;
    }
    __syncthreads();
    if (t < 8) {
        float m = -1e30f;
        for (int j = 0; j < 10; j++) m = fmaxf(m, logit[t * 10 + j]);
        float ssum = 0.f;
        for (int j = 0; j < 10; j++) ssum += expf(logit[t * 10 + j] - m);
        roff[t] = m + logf(ssum);
    }
    __syncthreads();
    if (t < 80) out[t] = logit[t] - roff[t / 10];
    if (t == 0) {
        float closs = 0.f;
        closs += sq[0] * (1.0f / 12582912.0f);
        closs += sq[1] * (1.0f / 78643200.0f);
        closs += sq[2] * (1.0f / 42205184.0f);
        closs += sq[3] * (1.0f / 18284544.0f);
        closs += sq[4] * (1.0f / 7028736.0f);
        out[80] = closs;
    }
}

// ---------------------------------------------------------------------------

extern "C" void kernel_launch(void* const* d_in, const int* in_sizes, int n_in,
                              void* d_out, int out_size, void* d_ws, size_t ws_size,
                              hipStream_t stream)
{
    static const int NSa[6] = {65536, 16384, 4096, 1024, 256, 64};
    static const int ESa[5] = {1048576, 262144, 65536, 16384, 4096};
    static const int COa[5] = {12, 20, 28, 36, 44};
    static const int CIa[5] = {1, 15, 23, 31, 39};

    const float* x0   = (const float*)d_in[0];
    const float* pos0 = (const float*)d_in[1];

    // ---- workspace layout (words), ~38 MB total ----
    int* wsw = (int*)d_ws;
    size_t off = 0;
    auto alw = [&](size_t n) -> size_t {
        size_t p = off; off += (n + 63) & ~(size_t)63; return p;
    };
    size_t degO[5], cdegO[5];
    for (int l = 2; l < 5; l++) degO[l]  = alw(NSa[l]);
    for (int l = 0; l < 5; l++) cdegO[l] = alw(NSa[l + 1]);
    size_t HO = alw(100);
    size_t zeroWords = off;                               // zero-init to here
    size_t rpO[5], crpO[5], eidO[5], cnidO[5];
    rpO[1] = alw(NSa[1] + 1);                             // rp1 (written by bucket1)
    for (int l = 2; l < 5; l++) rpO[l]  = alw(NSa[l] + 1);
    for (int l = 0; l < 5; l++) crpO[l] = alw(NSa[l + 1] + 1);
    for (int l = 2; l < 5; l++) eidO[l] = alw(ESa[l]);
    for (int l = 0; l < 5; l++) cnidO[l] = alw(NSa[l]);
    size_t tsO  = alw(64);
    size_t toO  = alw(64);
    size_t MO   = alw((size_t)TILES0 * NB0);
    size_t M2O  = alw((size_t)TILES0 * NB0);
    size_t ctO  = alw(NB0);
    size_t bsO  = alw(NB0 + 1);
    size_t payO = alw((size_t)ESa[0] * 4);                // seg0 16B records
    size_t M1O  = alw((size_t)TILES1 * NB1);
    size_t M21O = alw((size_t)TILES1 * NB1);
    size_t ct1O = alw(NB1);
    size_t bs1O = alw(NB1 + 1);
    size_t pay1O = alw((size_t)ESa[1] * 4);               // seg1 16B records
    size_t rec1O = alw((size_t)ESa[1] * 4);               // seg1 sorted records
    size_t yO   = alw((size_t)65536 * 12);
    size_t sqO  = alw(8);
    size_t xnO[5], pnO[5];
    for (int l = 0; l < 5; l++) xnO[l] = alw((size_t)NSa[l + 1] * (COa[l] + 3));
    for (int l = 0; l < 5; l++) pnO[l] = alw((size_t)NSa[l + 1] * 3);

    hipMemsetAsync(d_ws, 0, zeroWords * 4, stream);

    // ---- segs 2-9 descriptor (edge segs 2-4 + cluster segs 0-4) ----
    SegArgs sa{};
    int nseg = 0;
    for (int l = 2; l < 5; l++) {
        sa.idx[nseg] = (const int*)d_in[3 + 10 * l];
        sa.cnt[nseg] = wsw + degO[l];
        sa.rp [nseg] = wsw + rpO[l];
        sa.out[nseg] = wsw + eidO[l];
        sa.n  [nseg] = ESa[l];
        sa.nb [nseg] = NSa[l];
        nseg++;
    }
    for (int l = 0; l < 5; l++) {
        sa.idx[nseg] = (const int*)d_in[5 + 10 * l];
        sa.cnt[nseg] = wsw + cdegO[l];
        sa.rp [nseg] = wsw + crpO[l];
        sa.out[nseg] = wsw + cnidO[l];
        sa.n  [nseg] = NSa[l];
        sa.nb [nseg] = NSa[l + 1];
        nseg++;
    }
    ScanAux sx{};
    int tiles = 0, btiles = 0;
    for (int s = 0; s < nseg; s++) {
        int lg = 31 - __builtin_clz(sa.nb[s]);
        sa.shift[s] = lg - 3;
        sa.tstart[s] = tiles;
        tiles += (sa.n[s] + 255) / 256;
        sx.sstart[s] = btiles;
        btiles += (sa.nb[s] + 4095) / 4096;
    }
    for (int s = nseg; s <= 10; s++) {
        sa.tstart[s] = tiles;
        sx.sstart[s] = btiles;
        if (s < 10) {
            sa.idx[s] = sa.idx[nseg - 1]; sa.cnt[s] = sa.cnt[nseg - 1];
            sa.rp[s] = sa.rp[nseg - 1];   sa.out[s] = sa.out[nseg - 1];
            sa.n[s] = 0; sa.nb[s] = 8; sa.shift[s] = 0;
        }
    }
    sx.T = btiles;
    sx.tilesum = wsw + tsO;
    sx.tileoff = wsw + toO;
    int histBlocks = tiles * NBUCK;

    float4* pay2 = (float4*)(wsw + payO);
    float4* pay1 = (float4*)(wsw + pay1O);
    float4* rec1 = (float4*)(wsw + rec1O);
    float*  Hp   = (float*)(wsw + HO);

    HArgs ha{};
    int bs = 0;
    ha.bstart[0] = 0;
    ha.eattr[0] = (const float*)d_in[4];
    ha.w1[0] = (const float*)d_in[6];
    ha.b1[0] = (const float*)d_in[7];
    ha.E[0] = 0;
    for (int l = 1; l < 5; l++) {
        ha.eattr[l] = (const float*)d_in[4 + 10 * l];
        ha.w1[l]    = (const float*)d_in[6 + 10 * l];
        ha.b1[l]    = (const float*)d_in[7 + 10 * l];
        ha.E[l]     = ESa[l];
        ha.bstart[l] = bs;
        bs += (ESa[l] + 256 * 32 - 1) / (256 * 32);
    }
    ha.bstart[5] = bs;
    ha.H = Hp;

    WArgs wa{};
    for (int l = 0; l < 5; l++) {
        wa.w2[l]   = (const float*)d_in[8 + 10 * l];
        wa.b2[l]   = (const float*)d_in[9 + 10 * l];
        wa.cico[l] = CIa[l] * COa[l];
        wa.E[l]    = ESa[l];
    }
    wa.H  = Hp;
    wa.sq = (float*)(wsw + sqO);

    // ---- K2: cnt0 | cnt1 | hist_all | hstats ----
    countA_k<<<TILES0 + TILES1 + histBlocks + bs, 256, 0, stream>>>(
        sa, ha, (const int*)d_in[3], (const int*)d_in[13],
        wsw + MO, wsw + M1O, histBlocks);
    // ---- K3: colscan0 | colscan1 | scanA ----
    scanP1_k<<<NB0 + NB1 + btiles, 256, 0, stream>>>(
        sa, sx, wsw + MO, wsw + M2O, wsw + ctO,
        wsw + M1O, wsw + M21O, wsw + ct1O);
    // ---- K4: bktscan0 | scanB | bktscan1 ----
    scanP2_k<<<3, 512, 0, stream>>>(sa, sx, wsw + ctO, wsw + bsO,
                                    wsw + ct1O, wsw + bs1O);
    // ---- K5: scanC | part0 | part1 ----
    scanP3_k<<<btiles + TILES0 + TILES1, 256, 0, stream>>>(
        sa, sx,
        (const int*)d_in[2], (const int*)d_in[3], (const float*)d_in[4],
        x0, wsw + M2O, wsw + bsO, pay2,
        (const float*)d_in[6], (const float*)d_in[7], Hp,
        (const int*)d_in[12], (const int*)d_in[13], (const float*)d_in[14],
        wsw + M21O, wsw + bs1O, pay1);

    float* yb = (float*)(wsw + yO);

    // ---- K6: scatter_all | conv0c | wstats | bucket1 ----
    scatC_k<<<histBlocks + NB0 + 5 + NB1, 256, 0, stream>>>(
        sa, wa, histBlocks, pay2, wsw + bsO,
        (const float*)d_in[8], (const float*)d_in[9],
        (const float*)d_in[10], (const float*)d_in[11], x0, yb,
        pay1, wsw + bs1O, wsw + rpO[1], rec1);

    pool_k<12><<<(NSa[1] * 15 + 255) / 256, 256, 0, stream>>>(
        NSa[1], wsw + crpO[0], wsw + cnidO[0], yb, pos0,
        (float*)(wsw + xnO[0]), (float*)(wsw + pnO[0]));

    // ---- level 1: streaming conv ----
    conv1s_k<<<NSa[1], 256, 0, stream>>>(
        wsw + rpO[1], rec1,
        (const float*)d_in[16], (const float*)d_in[17],
        (const float*)d_in[18], (const float*)d_in[19],
        (const float*)d_in[20], (const float*)d_in[21],
        (const float*)(wsw + xnO[0]), yb);
    pool_k<20><<<(NSa[2] * 23 + 255) / 256, 256, 0, stream>>>(
        NSa[2], wsw + crpO[1], wsw + cnidO[1], yb,
        (const float*)(wsw + pnO[0]),
        (float*)(wsw + xnO[1]), (float*)(wsw + pnO[1]));

    // ---- levels 2-4 ----
#define LVLC(l, CI_, CO_) do {                                                 \
    const float* xin   = (const float*)(wsw + xnO[(l) - 1]);                   \
    const float* posin = (const float*)(wsw + pnO[(l) - 1]);                   \
    int N = NSa[(l)], NN = NSa[(l) + 1];                                       \
    coop_conv_k<CI_, CO_><<<N, 256, 0, stream>>>(                              \
        wsw + rpO[(l)], wsw + eidO[(l)],                                       \
        (const int*)d_in[2 + 10 * (l)], (const float*)d_in[4 + 10 * (l)],      \
        (const float*)d_in[6 + 10 * (l)], (const float*)d_in[7 + 10 * (l)],    \
        (const float*)d_in[8 + 10 * (l)], (const float*)d_in[9 + 10 * (l)],    \
        (const float*)d_in[10 + 10 * (l)], (const float*)d_in[11 + 10 * (l)],  \
        xin, yb);                                                              \
    pool_k<CO_><<<(NN * ((CO_) + 3) + 255) / 256, 256, 0, stream>>>(           \
        NN, wsw + crpO[(l)], wsw + cnidO[(l)], yb, posin,                      \
        (float*)(wsw + xnO[(l)]), (float*)(wsw + pnO[(l)]));                   \
} while (0)

    LVLC(2, 23, 28);
    LVLC(3, 31, 36);
    LVLC(4, 39, 44);
#undef LVLC

    fc_k<<<1, 128, 0, stream>>>((const float*)(wsw + xnO[4]),
                                (const float*)d_in[52], (const float*)d_in[53],
                                wa.sq, (float*)d_out);
}